// Round 9
// baseline (502.869 us; speedup 1.0000x reference)
//
#include <hip/hip_runtime.h>
#include <hip/hip_bf16.h>
#include <math.h>

typedef __bf16 bf16_t;
typedef __bf16 bf16x8 __attribute__((ext_vector_type(8)));
typedef __bf16 bf16x4 __attribute__((ext_vector_type(4)));
typedef float  f32x4  __attribute__((ext_vector_type(4)));

#define T_STEPS 32
#define BATCH   64
#define DIN     512
#define HID     512
#define VOCAB   32000
#define FFEAT   768
#define ROWS    2048   /* T*B */
#define G3      1536   /* 3*H */
#define NBLK_A  32

#define EPI_F32  0
#define EPI_BF16 1
#define EPI_TANH 2

#define GLOAD16(gp, lp) __builtin_amdgcn_global_load_lds( \
    (const __attribute__((address_space(1))) void*)(gp),  \
    (__attribute__((address_space(3))) void*)(lp), 16, 0, 0)

// ===========================================================================
// gemm_v: 256x256 8-phase GEMM (guide §5 template) -- VOCAB pass.
// e = exp(A@B^T + bias) -> bf16 ecache + fp32 partial row sums.
// R9: epilogue stages the 256x256 bf16 tile in LDS (16B-chunk XOR swizzle,
// phys = c ^ ((row&7)<<2); writes ~2-way banks = free, reads = volume floor)
// then stores coalesced 512B row segments -- replaces 128 scattered
// global_store_short per thread (32B segments, ~50% write efficiency).
// ===========================================================================
#define PHASEV(BUF, MH, NH, STAGE_STMT, GATE_STMT)                            \
  {                                                                           \
    bf16x8 af_[8], bf_[4];                                                    \
    _Pragma("unroll")                                                         \
    for (int m2 = 0; m2 < 4; ++m2) {                                          \
      const int row = wm * 64 + m2 * 16 + la;                                 \
      _Pragma("unroll")                                                       \
      for (int ks = 0; ks < 2; ++ks) {                                        \
        const int sl = (ks * 4 + lg) ^ (row & 7);                             \
        af_[m2 * 2 + ks] =                                                    \
            *(const bf16x8*)&lds[((BUF)*4 + (MH)) * 8192 + row * 64 + sl * 8];\
      }                                                                       \
    }                                                                         \
    _Pragma("unroll")                                                         \
    for (int n2 = 0; n2 < 2; ++n2) {                                          \
      const int row = wn * 32 + n2 * 16 + la;                                 \
      _Pragma("unroll")                                                       \
      for (int ks = 0; ks < 2; ++ks) {                                        \
        const int sl = (ks * 4 + lg) ^ (row & 7);                             \
        bf_[n2 * 2 + ks] =                                                    \
            *(const bf16x8*)&lds[((BUF)*4 + 2 + (NH)) * 8192 + row * 64 + sl * 8];\
      }                                                                       \
    }                                                                         \
    STAGE_STMT;                                                               \
    GATE_STMT;                                                                \
    __builtin_amdgcn_s_barrier();                                             \
    __builtin_amdgcn_s_setprio(1);                                            \
    _Pragma("unroll")                                                         \
    for (int m2 = 0; m2 < 4; ++m2)                                            \
      _Pragma("unroll")                                                       \
      for (int n2 = 0; n2 < 2; ++n2)                                          \
        _Pragma("unroll")                                                     \
        for (int ks = 0; ks < 2; ++ks)                                        \
          acc[(MH)*4 + m2][(NH)*2 + n2] =                                     \
              __builtin_amdgcn_mfma_f32_16x16x32_bf16(                        \
                  af_[m2*2+ks], bf_[n2*2+ks],                                 \
                  acc[(MH)*4 + m2][(NH)*2 + n2], 0, 0, 0);                    \
    __builtin_amdgcn_s_setprio(0);                                            \
    __builtin_amdgcn_s_barrier();                                             \
  }

template<int KD>
__global__ __launch_bounds__(512, 2) void gemm_v(
    const bf16_t* __restrict__ A, const bf16_t* __restrict__ B,
    const float* __restrict__ bias, bf16_t* __restrict__ ecache,
    float* __restrict__ partial, int M, int N, int NB)
{
  __shared__ bf16_t lds[2 * 4 * 8192];   // 128 KB (K-loop bufs; reused by epi)
  __shared__ float psum[256][4];
  const int tid = threadIdx.x;
  const int lane = tid & 63, wv = tid >> 6;
  const int wm = wv >> 2, wn = wv & 3;
  const int la = lane & 15, lg = lane >> 4;

  // bn-major XCD-chunk swizzle (nwg = NB * M/256, multiple of 8)
  const int lin = blockIdx.x;
  const int mt = M >> 8;                       // 8
  const int cpx = (NB * mt) >> 3;
  const int wg = (lin & 7) * cpx + (lin >> 3);
  const int bn = wg / mt, bm = wg - bn * mt;

  auto stageA = [&](int buf, int h, int kt) {
    const size_t base = (size_t)(bm * 256 + h * 128) * KD + (size_t)kt * 64;
#pragma unroll
    for (int q = 0; q < 2; ++q) {
      const int L = q * 512 + tid;
      const int row = L >> 3, sl = L & 7;
      const int c = sl ^ (row & 7);
      GLOAD16(A + base + (size_t)row * KD + c * 8,
              &lds[(buf * 4 + h) * 8192 + L * 8]);
    }
  };
  auto stageB = [&](int buf, int h, int kt) {
    const size_t base = (size_t)(bn * 256 + h * 128) * KD + (size_t)kt * 64;
#pragma unroll
    for (int q = 0; q < 2; ++q) {
      const int L = q * 512 + tid;
      const int row = L >> 3, sl = L & 7;
      const int c = sl ^ (row & 7);
      GLOAD16(B + base + (size_t)row * KD + c * 8,
              &lds[(buf * 4 + 2 + h) * 8192 + L * 8]);
    }
  };

  f32x4 acc[8][4] = {};
  constexpr int NITER = KD >> 7;               // 4 for K=512

  stageA(0, 0, 0); stageB(0, 0, 0); stageA(0, 1, 0); stageB(0, 1, 0);
  stageA(1, 0, 1); stageB(1, 0, 1);
  asm volatile("s_waitcnt vmcnt(4)" ::: "memory");
  __builtin_amdgcn_s_barrier();

#pragma unroll
  for (int it = 0; it < NITER; ++it) {
    const int t0 = 2 * it;
    const bool lastI = (it == NITER - 1);
    PHASEV(0, 0, 0, { stageA(1, 1, t0 + 1); }, ;)
    PHASEV(0, 0, 1, { stageB(1, 1, t0 + 1); }, ;)
    PHASEV(0, 1, 0, { if (!lastI) stageA(0, 0, t0 + 2); }, ;)
    PHASEV(0, 1, 1, { if (!lastI) stageB(0, 0, t0 + 2); },
           { if (lastI) { asm volatile("s_waitcnt vmcnt(0)" ::: "memory"); }
             else       { asm volatile("s_waitcnt vmcnt(4)" ::: "memory"); } })
    PHASEV(1, 0, 0, { if (!lastI) stageA(0, 1, t0 + 2); }, ;)
    PHASEV(1, 0, 1, { if (!lastI) stageB(0, 1, t0 + 2); }, ;)
    PHASEV(1, 1, 0, { if (!lastI) stageA(1, 0, t0 + 3); }, ;)
    PHASEV(1, 1, 1, { if (!lastI) stageB(1, 0, t0 + 3); },
           { if (!lastI) { asm volatile("s_waitcnt vmcnt(4)" ::: "memory"); } })
  }

  // ---- epilogue: exp -> LDS-staged bf16 tile + fp32 row sums --------------
  float bv[4];
#pragma unroll
  for (int nj = 0; nj < 4; ++nj) {
    const int col = bn * 256 + (nj >> 1) * 128 + wn * 32 + (nj & 1) * 16 + la;
    bv[nj] = bias[col];
  }
  unsigned int* ldsw = (unsigned int*)lds;
  const int odd = la & 1;
#pragma unroll
  for (int mi = 0; mi < 8; ++mi) {
#pragma unroll
    for (int rr = 0; rr < 4; ++rr) {
      const int rowl = (mi >> 2) * 128 + wm * 64 + (mi & 3) * 16 + lg * 4 + rr;
      float vsum = 0.f;
#pragma unroll
      for (int nj = 0; nj < 4; ++nj) {
        const float e = expf(acc[mi][nj][rr] + bv[nj]);
        vsum += e;
        const unsigned int mine =
            (unsigned int)__builtin_bit_cast(unsigned short, (bf16_t)e);
        const unsigned int other = (unsigned int)__shfl_xor((int)mine, 1);
        if ((odd == 0) == (rr < 2)) {   // parity-split: all 64 lanes busy
          const unsigned int pk = odd ? (other | (mine << 16))
                                      : (mine | (other << 16));
          const int cloc = (nj >> 1) * 128 + wn * 32 + (nj & 1) * 16 + (la & ~1);
          const int cw = cloc >> 1;              // u32 col within row (0..127)
          const int phys = (cw >> 2) ^ ((rowl & 7) << 2);
          ldsw[rowl * 128 + phys * 4 + (cw & 3)] = pk;
        }
      }
      vsum += __shfl_xor(vsum, 1);
      vsum += __shfl_xor(vsum, 2);
      vsum += __shfl_xor(vsum, 4);
      vsum += __shfl_xor(vsum, 8);
      if (la == 0) psum[rowl][wn] = vsum;
    }
  }
  __syncthreads();
  // coalesced read-back: half-wave = one full 512B row segment
#pragma unroll
  for (int i = 0; i < 16; ++i) {
    const int rowl = (tid >> 5) * 16 + i;
    const int c16 = tid & 31;
    const int phys = c16 ^ ((rowl & 7) << 2);
    bf16x8 v = *(const bf16x8*)&lds[rowl * 256 + phys * 8];
    *(bf16x8*)&ecache[(size_t)(bm * 256 + rowl) * N + bn * 256 + c16 * 8] = v;
  }
  if (tid < 256) {
    partial[(size_t)(bm * 256 + tid) * NB + bn] =
        psum[tid][0] + psum[tid][1] + psum[tid][2] + psum[tid][3];
  }
}

// ---------------------------------------------------------------------------
// 128x128 LDS GEMM (R6 pipeline, K templated) for gi/QKV/fc/h2o.
// ---------------------------------------------------------------------------
template<int EPI, int KD>
__global__ __launch_bounds__(256) void gemm_lds(
    const bf16_t* __restrict__ A, const bf16_t* __restrict__ B,
    const float* __restrict__ bias, void* __restrict__ out, int M, int N)
{
  __shared__ bf16_t As[3][128 * 32];
  __shared__ bf16_t Bs[3][128 * 32];

  const int lane = threadIdx.x & 63;
  const int wv   = threadIdx.x >> 6;
  const int wm = wv >> 1, wn = wv & 1;
  const int bn = blockIdx.x, bm = blockIdx.y;
  const int la = lane & 15, lg = lane >> 4;
  const int tid = threadIdx.x;

  auto stage = [&](int buf, int k0) {
#pragma unroll
    for (int q = 0; q < 2; ++q) {
      const int idx = q * 256 + tid;
      const int row = idx >> 2, c = idx & 3;
      const int gch = c ^ ((row >> 1) & 3);
      GLOAD16(A + (size_t)(bm * 128 + row) * KD + k0 + gch * 8, &As[buf][idx * 8]);
      GLOAD16(B + (size_t)(bn * 128 + row) * KD + k0 + gch * 8, &Bs[buf][idx * 8]);
    }
  };
  const int rdch = (lg ^ ((la >> 1) & 3)) * 8;

  f32x4 acc[4][4] = {};
  constexpr int NT = KD >> 5;
  stage(0, 0);
  stage(1, 32);
  for (int kt = 0; kt < NT; ++kt) {
    if (kt + 1 < NT) {
      asm volatile("s_waitcnt vmcnt(4)" ::: "memory");
    } else {
      asm volatile("s_waitcnt vmcnt(0)" ::: "memory");
    }
    __builtin_amdgcn_s_barrier();
    __builtin_amdgcn_sched_barrier(0);
    if (kt + 2 < NT) stage((kt + 2) % 3, (kt + 2) * 32);
    const bf16_t* Ab = As[kt % 3];
    const bf16_t* Bb = Bs[kt % 3];
    bf16x8 a[4], b[4];
#pragma unroll
    for (int i = 0; i < 4; ++i)
      a[i] = *(const bf16x8*)(Ab + (wm * 64 + i * 16 + la) * 32 + rdch);
#pragma unroll
    for (int j = 0; j < 4; ++j)
      b[j] = *(const bf16x8*)(Bb + (wn * 64 + j * 16 + la) * 32 + rdch);
    __builtin_amdgcn_s_setprio(1);
#pragma unroll
    for (int i = 0; i < 4; ++i)
#pragma unroll
      for (int j = 0; j < 4; ++j)
        acc[i][j] = __builtin_amdgcn_mfma_f32_16x16x32_bf16(a[i], b[j], acc[i][j], 0, 0, 0);
    __builtin_amdgcn_s_setprio(0);
  }

  const int m0 = bm * 128 + wm * 64;
  const int n0 = bn * 128 + wn * 64;
  float bv4[4];
#pragma unroll
  for (int j = 0; j < 4; ++j) bv4[j] = bias[n0 + j * 16 + la];
#pragma unroll
  for (int i = 0; i < 4; ++i) {
#pragma unroll
    for (int r = 0; r < 4; ++r) {
      const int row = m0 + i * 16 + lg * 4 + r;
#pragma unroll
      for (int j = 0; j < 4; ++j) {
        const int col = n0 + j * 16 + la;
        float v = acc[i][j][r] + bv4[j];
        if constexpr (EPI == EPI_F32) {
          ((float*)out)[(size_t)row * N + col] = v;
        } else if constexpr (EPI == EPI_BF16) {
          ((bf16_t*)out)[(size_t)row * N + col] = (bf16_t)v;
        } else {
          ((bf16_t*)out)[(size_t)row * N + col] = (bf16_t)tanhf(v);
        }
      }
    }
  }
}

// ---------------------------------------------------------------------------
// Phase A: sequential GRU recurrence. Pure 32-block version (R9: cast crew
// un-fused -- disambiguates whether its HBM traffic was inflating this
// latency-bound loop's L3 round-trips).
// ---------------------------------------------------------------------------
__global__ __launch_bounds__(256) void phaseA_k(
    const bf16_t* __restrict__ Wg, const float* __restrict__ bhh,
    const float* __restrict__ gi, const float* __restrict__ ct,
    unsigned int* __restrict__ hbuf, bf16_t* __restrict__ Xall,
    int* __restrict__ flags)
{
  __shared__ bf16_t Wl[48 * 520];
  __shared__ float bl[48];
  const int tid = threadIdx.x, blk = blockIdx.x;

  for (int i = tid; i < 48 * 64; i += 256) {
    const int rw = i >> 6, ch = (i & 63) << 3;
    *(bf16x8*)(Wl + rw * 520 + ch) = *(const bf16x8*)(Wg + (size_t)(blk * 48 + rw) * 512 + ch);
  }
  if (tid < 48) bl[tid] = bhh[blk * 48 + tid];
  __syncthreads();

  const int lane = tid & 63, wv = tid >> 6;
  const int la = lane & 15, lg = lane >> 4;
  const int jcol = blk * 16 + la;
  const int rowA = wv * 16 + la;

  const float blr = bl[la], blz = bl[16 + la], bln = bl[32 + la];
  float hprev[4], ctv[4];
#pragma unroll
  for (int r = 0; r < 4; ++r) {
    hprev[r] = 0.f;
    ctv[r] = ct[(size_t)(wv * 16 + lg * 4 + r) * HID + jcol];
  }

  for (int t = 0; t < T_STEPS; ++t) {
    const float* girow = gi + (size_t)t * BATCH * G3 + (size_t)blk * 48;
    float gv[12];
#pragma unroll
    for (int r = 0; r < 4; ++r) {
      const float* gp = girow + (size_t)(wv * 16 + lg * 4 + r) * G3;
      gv[r * 3 + 0] = gp[la];
      gv[r * 3 + 1] = gp[16 + la];
      gv[r * 3 + 2] = gp[32 + la];
    }
    if (t > 0) {
      if (lane < 32) {
        while (__hip_atomic_load(&flags[(lane * 4 + wv) * 16], __ATOMIC_RELAXED,
                                 __HIP_MEMORY_SCOPE_AGENT) < t) { }
      }
      asm volatile("" ::: "memory");
    }
    const unsigned long long* hb =
        (const unsigned long long*)(hbuf + (size_t)(t & 1) * 16384);
    bf16x8 af[16];
#pragma unroll
    for (int q = 0; q < 16; ++q) {
      union { unsigned long long u[2]; bf16x8 v; } c;
      const size_t bidx = (size_t)(2 * q + (lg >> 1)) * 256 + rowA * 4 + (lg & 1) * 2;
      c.u[0] = __hip_atomic_load(hb + bidx,     __ATOMIC_RELAXED, __HIP_MEMORY_SCOPE_AGENT);
      c.u[1] = __hip_atomic_load(hb + bidx + 1, __ATOMIC_RELAXED, __HIP_MEMORY_SCOPE_AGENT);
      af[q] = c.v;
    }
    f32x4 acc0 = {}, acc1 = {}, acc2 = {};
#pragma unroll
    for (int q = 0; q < 16; ++q) {
      const bf16_t* wp = Wl + q * 32 + lg * 8;
      bf16x8 b0 = *(const bf16x8*)(wp + (0 * 16 + la) * 520);
      bf16x8 b1 = *(const bf16x8*)(wp + (1 * 16 + la) * 520);
      bf16x8 b2 = *(const bf16x8*)(wp + (2 * 16 + la) * 520);
      acc0 = __builtin_amdgcn_mfma_f32_16x16x32_bf16(af[q], b0, acc0, 0, 0, 0);
      acc1 = __builtin_amdgcn_mfma_f32_16x16x32_bf16(af[q], b1, acc1, 0, 0, 0);
      acc2 = __builtin_amdgcn_mfma_f32_16x16x32_bf16(af[q], b2, acc2, 0, 0, 0);
    }
    float h1v[4];
#pragma unroll
    for (int r = 0; r < 4; ++r) {
      const float ghr = acc0[r] + blr;
      const float ghz = acc1[r] + blz;
      const float ghn = acc2[r] + bln;
      const float rr = 1.f / (1.f + expf(-(gv[r * 3 + 0] + ghr)));
      const float zz = 1.f / (1.f + expf(-(gv[r * 3 + 1] + ghz)));
      const float nn = tanhf(gv[r * 3 + 2] + rr * ghn);
      h1v[r] = (1.f - zz) * nn + zz * hprev[r];
      hprev[r] = h1v[r];
    }
    unsigned int* hn = hbuf + (size_t)((t + 1) & 1) * 16384 + blk * 512;
#pragma unroll
    for (int r = 0; r < 4; ++r) {
      const int row = wv * 16 + lg * 4 + r;
      const unsigned int mine =
          (unsigned int)__builtin_bit_cast(unsigned short, (bf16_t)h1v[r]);
      const unsigned int other = (unsigned int)__shfl_xor((int)mine, 1);
      if ((la & 1) == 0) {
        __hip_atomic_store(hn + row * 8 + (la >> 1), mine | (other << 16),
                           __ATOMIC_RELAXED, __HIP_MEMORY_SCOPE_AGENT);
      }
    }
    asm volatile("s_waitcnt vmcnt(0)" ::: "memory");
    if (lane == 0) {
      __hip_atomic_store(&flags[(blk * 4 + wv) * 16], t + 1, __ATOMIC_RELAXED,
                         __HIP_MEMORY_SCOPE_AGENT);
    }
#pragma unroll
    for (int r = 0; r < 4; ++r) {
      const int row = wv * 16 + lg * 4 + r;
      Xall[((size_t)t * BATCH + row) * HID + jcol] = (bf16_t)(h1v[r] * ctv[r]);
    }
  }
}

// ---------------------------------------------------------------------------
__global__ __launch_bounds__(256) void attn_k(const bf16_t* __restrict__ QKV,
                                              bf16_t* __restrict__ attO)
{
  __shared__ float sq[4][512], sk[4][512], sv[4][512], sw[4][64];
  const int tid = threadIdx.x;
  const int wv = tid >> 6, lane = tid & 63;
  const int row = blockIdx.x * 4 + wv;
  const bf16_t* base = QKV + (size_t)row * G3;
  bf16x8 vq = *(const bf16x8*)(base + lane * 8);
  bf16x8 vk = *(const bf16x8*)(base + 512 + lane * 8);
  bf16x8 vv = *(const bf16x8*)(base + 1024 + lane * 8);
#pragma unroll
  for (int e = 0; e < 8; ++e) {
    sq[wv][lane * 8 + e] = (float)vq[e];
    sk[wv][lane * 8 + e] = (float)vk[e];
    sv[wv][lane * 8 + e] = (float)vv[e];
  }
  __syncthreads();
  const int h = lane >> 3, g = lane & 7;
  float s = 0.f;
#pragma unroll 16
  for (int d = 0; d < 64; ++d) s += sq[wv][h * 64 + d] * sk[wv][g * 64 + d];
  s *= (1.f / 64.f);
  float m = s;
  m = fmaxf(m, __shfl_xor(m, 1));
  m = fmaxf(m, __shfl_xor(m, 2));
  m = fmaxf(m, __shfl_xor(m, 4));
  const float e = expf(s - m);
  float sum = e;
  sum += __shfl_xor(sum, 1);
  sum += __shfl_xor(sum, 2);
  sum += __shfl_xor(sum, 4);
  sw[wv][lane] = e / sum;
  __syncthreads();
#pragma unroll
  for (int rep = 0; rep < 8; ++rep) {
    const int idx = rep * 64 + lane;
    const int hh = idx >> 6, d = idx & 63;
    float o = 0.f;
#pragma unroll
    for (int gg = 0; gg < 8; ++gg) o += sw[wv][hh * 8 + gg] * sv[wv][gg * 64 + d];
    attO[(size_t)row * HID + idx] = (bf16_t)o;
  }
}

// --------------------------- small prep kernels ----------------------------
__global__ __launch_bounds__(256) void cast_k(const float* __restrict__ src,
                                              bf16_t* __restrict__ dst, int n4)
{
  const int i = blockIdx.x * 256 + threadIdx.x;
  if (i >= n4) return;
  float4 v = ((const float4*)src)[i];
  bf16x4 o = {(bf16_t)v.x, (bf16_t)v.y, (bf16_t)v.z, (bf16_t)v.w};
  *(bf16x4*)(dst + (size_t)i * 4) = o;
}

__global__ __launch_bounds__(256) void cast5_k(
    const float* __restrict__ s0, const float* __restrict__ s1,
    const float* __restrict__ s2, const float* __restrict__ s3,
    const float* __restrict__ s4, bf16_t* __restrict__ Wqkv,
    bf16_t* __restrict__ WfcB, bf16_t* __restrict__ Wh2oB)
{
  const int seg = blockIdx.x >> 8;
  const int i = (blockIdx.x & 255) * 256 + threadIdx.x;
  const float* src = seg == 0 ? s0 : seg == 1 ? s1 : seg == 2 ? s2
                   : seg == 3 ? s3 : s4;
  bf16_t* dst = seg <= 2 ? Wqkv + (size_t)seg * HID * DIN
              : seg == 3 ? WfcB : Wh2oB;
  float4 v = ((const float4*)src)[i];
  bf16x4 o = {(bf16_t)v.x, (bf16_t)v.y, (bf16_t)v.z, (bf16_t)v.w};
  *(bf16x4*)(dst + (size_t)i * 4) = o;
}

__global__ __launch_bounds__(256) void perm_cast_k(const float* __restrict__ src,
                                                   bf16_t* __restrict__ dst)
{
  const int i = blockIdx.x * 256 + threadIdx.x;
  const int pg = i >> 7, kq = (i & 127) << 2;
  const int g = pg / 48, rem = pg - g * 48, sec = rem >> 4, jj = rem & 15;
  const int srow = sec * 512 + g * 16 + jj;
  float4 v = *(const float4*)(src + (size_t)srow * DIN + kq);
  bf16x4 o = {(bf16_t)v.x, (bf16_t)v.y, (bf16_t)v.z, (bf16_t)v.w};
  *(bf16x4*)(dst + (size_t)pg * DIN + kq) = o;
}

__global__ void perm_bias_k(const float* __restrict__ bih, const float* __restrict__ bhh,
                            float* __restrict__ bihp, float* __restrict__ bhhp)
{
  const int pg = blockIdx.x * 256 + threadIdx.x;
  if (pg >= G3) return;
  const int g = pg / 48, rem = pg - g * 48, sec = rem >> 4, jj = rem & 15;
  const int srow = sec * 512 + g * 16 + jj;
  bihp[pg] = bih[srow];
  bhhp[pg] = bhh[srow];
}

__global__ void bcat_k(const float* __restrict__ a, const float* __restrict__ b,
                       const float* __restrict__ c, float* __restrict__ d)
{
  const int i = blockIdx.x * 256 + threadIdx.x;
  if (i >= G3) return;
  d[i] = i < 512 ? a[i] : (i < 1024 ? b[i - 512] : c[i - 1024]);
}

__global__ __launch_bounds__(256) void yemb_k(const int* __restrict__ y,
                                              const float* __restrict__ embW,
                                              bf16_t* __restrict__ out)
{
  const int idx = blockIdx.x * 256 + threadIdx.x;
  const int rb = idx >> 6, c = (idx & 63) << 3;
  const int tok = y[rb];
  const float4* s = (const float4*)(embW + (size_t)tok * DIN + c);
  float4 v0 = s[0], v1 = s[1];
  bf16x8 o = {(bf16_t)v0.x, (bf16_t)v0.y, (bf16_t)v0.z, (bf16_t)v0.w,
              (bf16_t)v1.x, (bf16_t)v1.y, (bf16_t)v1.z, (bf16_t)v1.w};
  *(bf16x8*)(out + (size_t)rb * DIN + c) = o;
}

__global__ __launch_bounds__(256) void ct_k(const float* __restrict__ ctx,
                                            const float* __restrict__ Watt,
                                            const float* __restrict__ batt,
                                            float* __restrict__ ct)
{
  const int idx = blockIdx.x * 256 + threadIdx.x;
  const int b = idx >> 9, j = idx & 511;
  const float4* c4 = (const float4*)(ctx + (size_t)b * FFEAT);
  const float4* w4 = (const float4*)(Watt + (size_t)j * FFEAT);
  float s = batt[j];
  for (int q = 0; q < FFEAT / 4; ++q) {
    float4 cc = c4[q], ww = w4[q];
    s += cc.x * ww.x + cc.y * ww.y + cc.z * ww.z + cc.w * ww.w;
  }
  ct[idx] = tanhf(s);
}

__global__ __launch_bounds__(256) void reduce_rows(const float* __restrict__ partial,
                                                   float* __restrict__ rowsum, int NB)
{
  const int wv = threadIdx.x >> 6, lane = threadIdx.x & 63;
  const int row = blockIdx.x * 4 + wv;
  float s = 0.f;
  for (int c = lane; c < NB; c += 64) s += partial[(size_t)row * NB + c];
  for (int m = 1; m < 64; m <<= 1) s += __shfl_xor(s, m);
  if (lane == 0) rowsum[row] = s;
}

__global__ __launch_bounds__(256) void normalize_k(const bf16_t* __restrict__ e,
                                                   const float* __restrict__ rowsum,
                                                   float* __restrict__ out)
{
  const int row = blockIdx.y;
  const int c8 = blockIdx.x * 256 + threadIdx.x;
  if (c8 >= VOCAB / 8) return;
  const float inv = 1.0f / rowsum[row];
  const size_t base = (size_t)row * VOCAB + (size_t)c8 * 8;
  bf16x8 v = *(const bf16x8*)(e + base);
  float4 o0 = {(float)v[0] * inv, (float)v[1] * inv, (float)v[2] * inv, (float)v[3] * inv};
  float4 o1 = {(float)v[4] * inv, (float)v[5] * inv, (float)v[6] * inv, (float)v[7] * inv};
  *(float4*)(out + base) = o0;
  *(float4*)(out + base + 4) = o1;
}

// ---------------------------------------------------------------------------
extern "C" void kernel_launch(void* const* d_in, const int* in_sizes, int n_in,
                              void* d_out, int out_size, void* d_ws, size_t ws_size,
                              hipStream_t stream)
{
  const int*   y     = (const int*)  d_in[0];
  const float* ctx   = (const float*)d_in[1];
  const float* embW  = (const float*)d_in[2];
  const float* W_ih  = (const float*)d_in[3];
  const float* b_ih  = (const float*)d_in[4];
  const float* W_hh  = (const float*)d_in[5];
  const float* b_hh  = (const float*)d_in[6];
  const float* W_att = (const float*)d_in[7];
  const float* b_att = (const float*)d_in[8];
  const float* Wq    = (const float*)d_in[9];
  const float* bq    = (const float*)d_in[10];
  const float* Wk    = (const float*)d_in[11];
  const float* bk    = (const float*)d_in[12];
  const float* Wv    = (const float*)d_in[13];
  const float* bv    = (const float*)d_in[14];
  const float* Wfc   = (const float*)d_in[15];
  const float* bfc   = (const float*)d_in[16];
  const float* Wh2o  = (const float*)d_in[17];
  const float* bh2o  = (const float*)d_in[18];
  const float* W_out = (const float*)d_in[19];
  const float* b_out = (const float*)d_in[20];

  char* p = (char*)d_ws;
  auto alloc = [&](size_t bytes) {
    char* r = p;
    p += (bytes + 255) & ~(size_t)255;
    return r;
  };
  bf16_t* WoutB   = (bf16_t*)alloc((size_t)VOCAB * DIN * 2);
  bf16_t* WgIh    = (bf16_t*)alloc((size_t)G3 * DIN * 2);
  bf16_t* WgHh    = (bf16_t*)alloc((size_t)G3 * DIN * 2);
  bf16_t* Wqkv    = (bf16_t*)alloc((size_t)G3 * DIN * 2);
  bf16_t* WfcB    = (bf16_t*)alloc((size_t)HID * HID * 2);
  bf16_t* Wh2oB   = (bf16_t*)alloc((size_t)HID * HID * 2);
  float*  bIhP    = (float*)alloc(G3 * 4);
  float*  bHhP    = (float*)alloc(G3 * 4);
  float*  bQkv    = (float*)alloc(G3 * 4);
  bf16_t* Yemb    = (bf16_t*)alloc((size_t)ROWS * DIN * 2);
  float*  giP     = (float*)alloc((size_t)ROWS * G3 * 4);
  float*  ctB     = (float*)alloc((size_t)BATCH * HID * 4);
  unsigned int* hbuf = (unsigned int*)alloc((size_t)2 * 16384 * 4);
  bf16_t* Xall    = (bf16_t*)alloc((size_t)ROWS * DIN * 2);
  bf16_t* QKV     = (bf16_t*)alloc((size_t)ROWS * G3 * 2);
  bf16_t* attO    = (bf16_t*)alloc((size_t)ROWS * HID * 2);
  bf16_t* h2B     = (bf16_t*)alloc((size_t)ROWS * HID * 2);
  bf16_t* logit   = (bf16_t*)alloc((size_t)ROWS * DIN * 2);
  float*  partial = (float*)alloc((size_t)ROWS * 125 * 4);
  float*  rowsum  = (float*)alloc((size_t)ROWS * 4);
  int*    flags   = (int*)alloc(32 * 4 * 64);
  bf16_t* eCache  = (bf16_t*)alloc((size_t)ROWS * VOCAB * 2);   // 131 MB

  hipMemsetAsync(hbuf, 0, (size_t)2 * 16384 * 4, stream);
  hipMemsetAsync(flags, 0, 32 * 4 * 64, stream);

  // weight prep (W_out cast standalone again -- R9 disambiguation)
  cast_k<<<VOCAB * DIN / 4 / 256, 256, 0, stream>>>(W_out, WoutB, VOCAB * DIN / 4);
  cast5_k<<<1280, 256, 0, stream>>>(Wq, Wk, Wv, Wfc, Wh2o, Wqkv, WfcB, Wh2oB);
  perm_cast_k<<<768, 256, 0, stream>>>(W_ih, WgIh);
  perm_cast_k<<<768, 256, 0, stream>>>(W_hh, WgHh);
  perm_bias_k<<<6, 256, 0, stream>>>(b_ih, b_hh, bIhP, bHhP);
  bcat_k<<<6, 256, 0, stream>>>(bq, bk, bv, bQkv);
  yemb_k<<<512, 256, 0, stream>>>(y, embW, Yemb);
  ct_k<<<128, 256, 0, stream>>>(ctx, W_att, b_att, ctB);

  // gi = Yemb @ WgIh^T + bIhP  (fp32)
  gemm_lds<EPI_F32, DIN><<<dim3(12, 16), 256, 0, stream>>>(
      Yemb, WgIh, bIhP, giP, ROWS, G3);

  // GRU recurrence (pure, 32 blocks)
  phaseA_k<<<NBLK_A, 256, 0, stream>>>(WgHh, bHhP, giP, ctB, hbuf, Xall, flags);

  // QKV = X @ [Wq;Wk;Wv]^T + b
  gemm_lds<EPI_BF16, DIN><<<dim3(12, 16), 256, 0, stream>>>(
      Xall, Wqkv, bQkv, QKV, ROWS, G3);

  attn_k<<<512, 256, 0, stream>>>(QKV, attO);

  gemm_lds<EPI_BF16, HID><<<dim3(4, 16), 256, 0, stream>>>(
      attO, WfcB, bfc, h2B, ROWS, HID);

  gemm_lds<EPI_TANH, HID><<<dim3(4, 16), 256, 0, stream>>>(
      h2B, Wh2oB, bh2o, logit, ROWS, DIN);

  // vocab: single GEMM -> bf16 exp cache + partial sums (NB = 125)
  gemm_v<DIN><<<1000, 512, 0, stream>>>(
      logit, WoutB, b_out, eCache, partial, ROWS, VOCAB, 125);
  reduce_rows<<<512, 256, 0, stream>>>(partial, rowsum, 125);
  normalize_k<<<dim3(16, ROWS), 256, 0, stream>>>(eCache, rowsum, (float*)d_out);
}

// Round 10
// 455.380 us; speedup vs baseline: 1.1043x; 1.1043x over previous
//
#include <hip/hip_runtime.h>
#include <hip/hip_bf16.h>
#include <math.h>

typedef __bf16 bf16_t;
typedef __bf16 bf16x8 __attribute__((ext_vector_type(8)));
typedef __bf16 bf16x4 __attribute__((ext_vector_type(4)));
typedef float  f32x4  __attribute__((ext_vector_type(4)));

#define T_STEPS 32
#define BATCH   64
#define DIN     512
#define HID     512
#define VOCAB   32000
#define FFEAT   768
#define ROWS    2048   /* T*B */
#define G3      1536   /* 3*H */
#define NBLK_A  32

#define EPI_F32  0
#define EPI_BF16 1
#define EPI_TANH 2

#define GLOAD16(gp, lp) __builtin_amdgcn_global_load_lds( \
    (const __attribute__((address_space(1))) void*)(gp),  \
    (__attribute__((address_space(3))) void*)(lp), 16, 0, 0)

// ===========================================================================
// gemm_v: 256x256 8-phase GEMM -- VOCAB pass.
// R10 rebalance: phase = (M-half, K-slice), computing 4 m-frags x ALL 4
// n-frags x 1 k-slice = 16 MFMA from 4 A + 4 B ds_read_b128 (0.5 reads/MFMA,
// was 0.75 with the (MH,NH) quadrant split). LDS-read demand/CU-phase now
// ~256B/cyc ~= CU LDS read BW ~= MFMA cycles -> phases balanced.
// Stage schedule (buf0 = even tile, consumed ph1-4; buf1 = odd, ph5-8):
//   ph1: buf1.Ah1 + buf1.Bh0 (T2i+1)   ph5: buf0.Ah1 + buf0.Bh0 (T2i+2)
//   ph2: buf1.Bh1 (T2i+1)              ph6: buf0.Bh1 (T2i+2)
//   ph3: buf0.Ah0 (T2i+2)              ph7: buf1.Ah0 (T2i+3)
//   ph4: gate vmcnt(2)                 ph8: gate vmcnt(2)
// WAR per half: stage issued >=1 barrier after that half's last ds_read.
// Deadlines (loads/thread, steady state enters iter with 2 outstanding):
//   ph1+4=6, ph2+2=8, ph3+2=10, ph4 vmcnt(2) drains odd tile fully;
//   ph5+4=6, ph6+2=8, ph7+2=10, ph8 vmcnt(2) drains even tile. Last iter
//   skips T+2/T+3 stages, ph4 gate = vmcnt(0).
// Swizzle (T2, rule 21): LDS 16B slot s holds chunk c = s ^ (row&7); inverse
// on the GLOBAL src addr (gload_lds dest linear), same XOR on ds_read.
// Epilogue: exp -> paired u32 global stores (even lanes, shfl-packed).
// ===========================================================================
#define PHASEK(BUF, MH, KS, STAGE_STMT, GATE_STMT)                            \
  {                                                                           \
    bf16x8 af_[4], bf_[4];                                                    \
    _Pragma("unroll")                                                         \
    for (int m2 = 0; m2 < 4; ++m2) {                                          \
      const int row = wm * 64 + m2 * 16 + la;                                 \
      const int sl = ((KS) * 4 + lg) ^ (row & 7);                             \
      af_[m2] =                                                               \
          *(const bf16x8*)&lds[((BUF)*4 + (MH)) * 8192 + row * 64 + sl * 8];  \
    }                                                                         \
    _Pragma("unroll")                                                         \
    for (int nj = 0; nj < 4; ++nj) {                                          \
      const int row = wn * 32 + (nj & 1) * 16 + la;                           \
      const int sl = ((KS) * 4 + lg) ^ (row & 7);                             \
      bf_[nj] =                                                               \
          *(const bf16x8*)&lds[((BUF)*4 + 2 + (nj >> 1)) * 8192 + row * 64 + sl * 8];\
    }                                                                         \
    STAGE_STMT;                                                               \
    GATE_STMT;                                                                \
    __builtin_amdgcn_s_barrier();                                             \
    __builtin_amdgcn_s_setprio(1);                                            \
    _Pragma("unroll")                                                         \
    for (int m2 = 0; m2 < 4; ++m2)                                            \
      _Pragma("unroll")                                                       \
      for (int nj = 0; nj < 4; ++nj)                                          \
        acc[(MH)*4 + m2][nj] =                                                \
            __builtin_amdgcn_mfma_f32_16x16x32_bf16(                          \
                af_[m2], bf_[nj], acc[(MH)*4 + m2][nj], 0, 0, 0);             \
    __builtin_amdgcn_s_setprio(0);                                            \
    __builtin_amdgcn_s_barrier();                                             \
  }

template<int KD>
__global__ __launch_bounds__(512, 2) void gemm_v(
    const bf16_t* __restrict__ A, const bf16_t* __restrict__ B,
    const float* __restrict__ bias, bf16_t* __restrict__ ecache,
    float* __restrict__ partial, int M, int N, int NB)
{
  __shared__ bf16_t lds[2 * 4 * 8192];   // 128 KB
  __shared__ float psum[256][4];
  const int tid = threadIdx.x;
  const int lane = tid & 63, wv = tid >> 6;
  const int wm = wv >> 2, wn = wv & 3;
  const int la = lane & 15, lg = lane >> 4;

  // bn-major XCD-chunk swizzle (nwg = NB * M/256, multiple of 8)
  const int lin = blockIdx.x;
  const int mt = M >> 8;                       // 8
  const int cpx = (NB * mt) >> 3;
  const int wg = (lin & 7) * cpx + (lin >> 3);
  const int bn = wg / mt, bm = wg - bn * mt;

  auto stageA = [&](int buf, int h, int kt) {
    const size_t base = (size_t)(bm * 256 + h * 128) * KD + (size_t)kt * 64;
#pragma unroll
    for (int q = 0; q < 2; ++q) {
      const int L = q * 512 + tid;
      const int row = L >> 3, sl = L & 7;
      const int c = sl ^ (row & 7);
      GLOAD16(A + base + (size_t)row * KD + c * 8,
              &lds[(buf * 4 + h) * 8192 + L * 8]);
    }
  };
  auto stageB = [&](int buf, int h, int kt) {
    const size_t base = (size_t)(bn * 256 + h * 128) * KD + (size_t)kt * 64;
#pragma unroll
    for (int q = 0; q < 2; ++q) {
      const int L = q * 512 + tid;
      const int row = L >> 3, sl = L & 7;
      const int c = sl ^ (row & 7);
      GLOAD16(B + base + (size_t)row * KD + c * 8,
              &lds[(buf * 4 + 2 + h) * 8192 + L * 8]);
    }
  };

  f32x4 acc[8][4] = {};
  constexpr int NITER = KD >> 7;               // 4 for K=512

  // prologue: T0 all 4 halves + T1.Ah0 (10 loads); vmcnt(2) -> T0 landed
  stageA(0, 0, 0); stageA(0, 1, 0); stageB(0, 0, 0); stageB(0, 1, 0);
  stageA(1, 0, 1);
  asm volatile("s_waitcnt vmcnt(2)" ::: "memory");
  __builtin_amdgcn_s_barrier();

#pragma unroll
  for (int it = 0; it < NITER; ++it) {
    const int t0 = 2 * it;
    const bool lastI = (it == NITER - 1);
    PHASEK(0, 0, 0, { stageA(1, 1, t0 + 1); stageB(1, 0, t0 + 1); }, ;)
    PHASEK(0, 0, 1, { stageB(1, 1, t0 + 1); }, ;)
    PHASEK(0, 1, 0, { if (!lastI) stageA(0, 0, t0 + 2); }, ;)
    PHASEK(0, 1, 1, { },
           { if (lastI) { asm volatile("s_waitcnt vmcnt(0)" ::: "memory"); }
             else       { asm volatile("s_waitcnt vmcnt(2)" ::: "memory"); } })
    PHASEK(1, 0, 0, { if (!lastI) { stageA(0, 1, t0 + 2); stageB(0, 0, t0 + 2); } }, ;)
    PHASEK(1, 0, 1, { if (!lastI) stageB(0, 1, t0 + 2); }, ;)
    PHASEK(1, 1, 0, { if (!lastI) stageA(1, 0, t0 + 3); }, ;)
    PHASEK(1, 1, 1, { },
           { if (!lastI) { asm volatile("s_waitcnt vmcnt(2)" ::: "memory"); } })
  }

  // ---- epilogue: e = exp(acc+bias) -> paired u32 stores + row sums --------
  float bv[4];
#pragma unroll
  for (int nj = 0; nj < 4; ++nj) {
    const int col = bn * 256 + (nj >> 1) * 128 + wn * 32 + (nj & 1) * 16 + la;
    bv[nj] = bias[col];
  }
  const int odd = la & 1;
#pragma unroll
  for (int mi = 0; mi < 8; ++mi) {
#pragma unroll
    for (int rr = 0; rr < 4; ++rr) {
      const int rowl = (mi >> 2) * 128 + wm * 64 + (mi & 3) * 16 + lg * 4 + rr;
      const int row = bm * 256 + rowl;
      float vsum = 0.f;
#pragma unroll
      for (int nj = 0; nj < 4; ++nj) {
        const float e = expf(acc[mi][nj][rr] + bv[nj]);
        vsum += e;
        const unsigned int mine =
            (unsigned int)__builtin_bit_cast(unsigned short, (bf16_t)e);
        const unsigned int other = (unsigned int)__shfl_xor((int)mine, 1);
        if (!odd) {
          const int col = bn * 256 + (nj >> 1) * 128 + wn * 32 + (nj & 1) * 16 + la;
          *(unsigned int*)&ecache[(size_t)row * N + col] = mine | (other << 16);
        }
      }
      vsum += __shfl_xor(vsum, 1);
      vsum += __shfl_xor(vsum, 2);
      vsum += __shfl_xor(vsum, 4);
      vsum += __shfl_xor(vsum, 8);
      if (la == 0) psum[rowl][wn] = vsum;
    }
  }
  __syncthreads();
  if (tid < 256) {
    partial[(size_t)(bm * 256 + tid) * NB + bn] =
        psum[tid][0] + psum[tid][1] + psum[tid][2] + psum[tid][3];
  }
}

// ---------------------------------------------------------------------------
// 128x128 LDS GEMM (R6 pipeline, K templated) for gi/QKV/fc/h2o.
// ---------------------------------------------------------------------------
template<int EPI, int KD>
__global__ __launch_bounds__(256) void gemm_lds(
    const bf16_t* __restrict__ A, const bf16_t* __restrict__ B,
    const float* __restrict__ bias, void* __restrict__ out, int M, int N)
{
  __shared__ bf16_t As[3][128 * 32];
  __shared__ bf16_t Bs[3][128 * 32];

  const int lane = threadIdx.x & 63;
  const int wv   = threadIdx.x >> 6;
  const int wm = wv >> 1, wn = wv & 1;
  const int bn = blockIdx.x, bm = blockIdx.y;
  const int la = lane & 15, lg = lane >> 4;
  const int tid = threadIdx.x;

  auto stage = [&](int buf, int k0) {
#pragma unroll
    for (int q = 0; q < 2; ++q) {
      const int idx = q * 256 + tid;
      const int row = idx >> 2, c = idx & 3;
      const int gch = c ^ ((row >> 1) & 3);
      GLOAD16(A + (size_t)(bm * 128 + row) * KD + k0 + gch * 8, &As[buf][idx * 8]);
      GLOAD16(B + (size_t)(bn * 128 + row) * KD + k0 + gch * 8, &Bs[buf][idx * 8]);
    }
  };
  const int rdch = (lg ^ ((la >> 1) & 3)) * 8;

  f32x4 acc[4][4] = {};
  constexpr int NT = KD >> 5;
  stage(0, 0);
  stage(1, 32);
  for (int kt = 0; kt < NT; ++kt) {
    if (kt + 1 < NT) {
      asm volatile("s_waitcnt vmcnt(4)" ::: "memory");
    } else {
      asm volatile("s_waitcnt vmcnt(0)" ::: "memory");
    }
    __builtin_amdgcn_s_barrier();
    __builtin_amdgcn_sched_barrier(0);
    if (kt + 2 < NT) stage((kt + 2) % 3, (kt + 2) * 32);
    const bf16_t* Ab = As[kt % 3];
    const bf16_t* Bb = Bs[kt % 3];
    bf16x8 a[4], b[4];
#pragma unroll
    for (int i = 0; i < 4; ++i)
      a[i] = *(const bf16x8*)(Ab + (wm * 64 + i * 16 + la) * 32 + rdch);
#pragma unroll
    for (int j = 0; j < 4; ++j)
      b[j] = *(const bf16x8*)(Bb + (wn * 64 + j * 16 + la) * 32 + rdch);
    __builtin_amdgcn_s_setprio(1);
#pragma unroll
    for (int i = 0; i < 4; ++i)
#pragma unroll
      for (int j = 0; j < 4; ++j)
        acc[i][j] = __builtin_amdgcn_mfma_f32_16x16x32_bf16(a[i], b[j], acc[i][j], 0, 0, 0);
    __builtin_amdgcn_s_setprio(0);
  }

  const int m0 = bm * 128 + wm * 64;
  const int n0 = bn * 128 + wn * 64;
  float bv4[4];
#pragma unroll
  for (int j = 0; j < 4; ++j) bv4[j] = bias[n0 + j * 16 + la];
#pragma unroll
  for (int i = 0; i < 4; ++i) {
#pragma unroll
    for (int r = 0; r < 4; ++r) {
      const int row = m0 + i * 16 + lg * 4 + r;
#pragma unroll
      for (int j = 0; j < 4; ++j) {
        const int col = n0 + j * 16 + la;
        float v = acc[i][j][r] + bv4[j];
        if constexpr (EPI == EPI_F32) {
          ((float*)out)[(size_t)row * N + col] = v;
        } else if constexpr (EPI == EPI_BF16) {
          ((bf16_t*)out)[(size_t)row * N + col] = (bf16_t)v;
        } else {
          ((bf16_t*)out)[(size_t)row * N + col] = (bf16_t)tanhf(v);
        }
      }
    }
  }
}

// ---------------------------------------------------------------------------
// Phase A: GRU recurrence (blocks 0..31) + fused W_out cast (blocks 32..223).
// R9 showed the fused cast is free (phaseA unchanged with/without crew).
// ---------------------------------------------------------------------------
__global__ __launch_bounds__(256) void phaseA_k(
    const bf16_t* __restrict__ Wg, const float* __restrict__ bhh,
    const float* __restrict__ gi, const float* __restrict__ ct,
    unsigned int* __restrict__ hbuf, bf16_t* __restrict__ Xall,
    int* __restrict__ flags, const float* __restrict__ Wout_f32,
    bf16_t* __restrict__ WoutB)
{
  __shared__ bf16_t Wl[48 * 520];
  __shared__ float bl[48];
  const int tid = threadIdx.x, blk = blockIdx.x;

  if (blk >= NBLK_A) {                          // cast crew
    const int NCB = gridDim.x - NBLK_A;
    const int n4 = VOCAB * DIN / 4;
    for (int i = (blk - NBLK_A) * 256 + tid; i < n4; i += NCB * 256) {
      float4 v = ((const float4*)Wout_f32)[i];
      bf16x4 o = {(bf16_t)v.x, (bf16_t)v.y, (bf16_t)v.z, (bf16_t)v.w};
      *(bf16x4*)(WoutB + (size_t)i * 4) = o;
    }
    return;
  }

  for (int i = tid; i < 48 * 64; i += 256) {
    const int rw = i >> 6, ch = (i & 63) << 3;
    *(bf16x8*)(Wl + rw * 520 + ch) = *(const bf16x8*)(Wg + (size_t)(blk * 48 + rw) * 512 + ch);
  }
  if (tid < 48) bl[tid] = bhh[blk * 48 + tid];
  __syncthreads();

  const int lane = tid & 63, wv = tid >> 6;
  const int la = lane & 15, lg = lane >> 4;
  const int jcol = blk * 16 + la;
  const int rowA = wv * 16 + la;

  const float blr = bl[la], blz = bl[16 + la], bln = bl[32 + la];
  float hprev[4], ctv[4];
#pragma unroll
  for (int r = 0; r < 4; ++r) {
    hprev[r] = 0.f;
    ctv[r] = ct[(size_t)(wv * 16 + lg * 4 + r) * HID + jcol];
  }

  for (int t = 0; t < T_STEPS; ++t) {
    const float* girow = gi + (size_t)t * BATCH * G3 + (size_t)blk * 48;
    float gv[12];
#pragma unroll
    for (int r = 0; r < 4; ++r) {
      const float* gp = girow + (size_t)(wv * 16 + lg * 4 + r) * G3;
      gv[r * 3 + 0] = gp[la];
      gv[r * 3 + 1] = gp[16 + la];
      gv[r * 3 + 2] = gp[32 + la];
    }
    if (t > 0) {
      if (lane < 32) {
        while (__hip_atomic_load(&flags[(lane * 4 + wv) * 16], __ATOMIC_RELAXED,
                                 __HIP_MEMORY_SCOPE_AGENT) < t) { }
      }
      asm volatile("" ::: "memory");
    }
    const unsigned long long* hb =
        (const unsigned long long*)(hbuf + (size_t)(t & 1) * 16384);
    bf16x8 af[16];
#pragma unroll
    for (int q = 0; q < 16; ++q) {
      union { unsigned long long u[2]; bf16x8 v; } c;
      const size_t bidx = (size_t)(2 * q + (lg >> 1)) * 256 + rowA * 4 + (lg & 1) * 2;
      c.u[0] = __hip_atomic_load(hb + bidx,     __ATOMIC_RELAXED, __HIP_MEMORY_SCOPE_AGENT);
      c.u[1] = __hip_atomic_load(hb + bidx + 1, __ATOMIC_RELAXED, __HIP_MEMORY_SCOPE_AGENT);
      af[q] = c.v;
    }
    f32x4 acc0 = {}, acc1 = {}, acc2 = {};
#pragma unroll
    for (int q = 0; q < 16; ++q) {
      const bf16_t* wp = Wl + q * 32 + lg * 8;
      bf16x8 b0 = *(const bf16x8*)(wp + (0 * 16 + la) * 520);
      bf16x8 b1 = *(const bf16x8*)(wp + (1 * 16 + la) * 520);
      bf16x8 b2 = *(const bf16x8*)(wp + (2 * 16 + la) * 520);
      acc0 = __builtin_amdgcn_mfma_f32_16x16x32_bf16(af[q], b0, acc0, 0, 0, 0);
      acc1 = __builtin_amdgcn_mfma_f32_16x16x32_bf16(af[q], b1, acc1, 0, 0, 0);
      acc2 = __builtin_amdgcn_mfma_f32_16x16x32_bf16(af[q], b2, acc2, 0, 0, 0);
    }
    float h1v[4];
#pragma unroll
    for (int r = 0; r < 4; ++r) {
      const float ghr = acc0[r] + blr;
      const float ghz = acc1[r] + blz;
      const float ghn = acc2[r] + bln;
      const float rr = 1.f / (1.f + expf(-(gv[r * 3 + 0] + ghr)));
      const float zz = 1.f / (1.f + expf(-(gv[r * 3 + 1] + ghz)));
      const float nn = tanhf(gv[r * 3 + 2] + rr * ghn);
      h1v[r] = (1.f - zz) * nn + zz * hprev[r];
      hprev[r] = h1v[r];
    }
    unsigned int* hn = hbuf + (size_t)((t + 1) & 1) * 16384 + blk * 512;
#pragma unroll
    for (int r = 0; r < 4; ++r) {
      const int row = wv * 16 + lg * 4 + r;
      const unsigned int mine =
          (unsigned int)__builtin_bit_cast(unsigned short, (bf16_t)h1v[r]);
      const unsigned int other = (unsigned int)__shfl_xor((int)mine, 1);
      if ((la & 1) == 0) {
        __hip_atomic_store(hn + row * 8 + (la >> 1), mine | (other << 16),
                           __ATOMIC_RELAXED, __HIP_MEMORY_SCOPE_AGENT);
      }
    }
    asm volatile("s_waitcnt vmcnt(0)" ::: "memory");
    if (lane == 0) {
      __hip_atomic_store(&flags[(blk * 4 + wv) * 16], t + 1, __ATOMIC_RELAXED,
                         __HIP_MEMORY_SCOPE_AGENT);
    }
#pragma unroll
    for (int r = 0; r < 4; ++r) {
      const int row = wv * 16 + lg * 4 + r;
      Xall[((size_t)t * BATCH + row) * HID + jcol] = (bf16_t)(h1v[r] * ctv[r]);
    }
  }
}

// ---------------------------------------------------------------------------
__global__ __launch_bounds__(256) void attn_k(const bf16_t* __restrict__ QKV,
                                              bf16_t* __restrict__ attO)
{
  __shared__ float sq[4][512], sk[4][512], sv[4][512], sw[4][64];
  const int tid = threadIdx.x;
  const int wv = tid >> 6, lane = tid & 63;
  const int row = blockIdx.x * 4 + wv;
  const bf16_t* base = QKV + (size_t)row * G3;
  bf16x8 vq = *(const bf16x8*)(base + lane * 8);
  bf16x8 vk = *(const bf16x8*)(base + 512 + lane * 8);
  bf16x8 vv = *(const bf16x8*)(base + 1024 + lane * 8);
#pragma unroll
  for (int e = 0; e < 8; ++e) {
    sq[wv][lane * 8 + e] = (float)vq[e];
    sk[wv][lane * 8 + e] = (float)vk[e];
    sv[wv][lane * 8 + e] = (float)vv[e];
  }
  __syncthreads();
  const int h = lane >> 3, g = lane & 7;
  float s = 0.f;
#pragma unroll 16
  for (int d = 0; d < 64; ++d) s += sq[wv][h * 64 + d] * sk[wv][g * 64 + d];
  s *= (1.f / 64.f);
  float m = s;
  m = fmaxf(m, __shfl_xor(m, 1));
  m = fmaxf(m, __shfl_xor(m, 2));
  m = fmaxf(m, __shfl_xor(m, 4));
  const float e = expf(s - m);
  float sum = e;
  sum += __shfl_xor(sum, 1);
  sum += __shfl_xor(sum, 2);
  sum += __shfl_xor(sum, 4);
  sw[wv][lane] = e / sum;
  __syncthreads();
#pragma unroll
  for (int rep = 0; rep < 8; ++rep) {
    const int idx = rep * 64 + lane;
    const int hh = idx >> 6, d = idx & 63;
    float o = 0.f;
#pragma unroll
    for (int gg = 0; gg < 8; ++gg) o += sw[wv][hh * 8 + gg] * sv[wv][gg * 64 + d];
    attO[(size_t)row * HID + idx] = (bf16_t)o;
  }
}

// --------------------------- small prep kernels ----------------------------
__global__ __launch_bounds__(256) void cast5_k(
    const float* __restrict__ s0, const float* __restrict__ s1,
    const float* __restrict__ s2, const float* __restrict__ s3,
    const float* __restrict__ s4, bf16_t* __restrict__ Wqkv,
    bf16_t* __restrict__ WfcB, bf16_t* __restrict__ Wh2oB)
{
  const int seg = blockIdx.x >> 8;
  const int i = (blockIdx.x & 255) * 256 + threadIdx.x;
  const float* src = seg == 0 ? s0 : seg == 1 ? s1 : seg == 2 ? s2
                   : seg == 3 ? s3 : s4;
  bf16_t* dst = seg <= 2 ? Wqkv + (size_t)seg * HID * DIN
              : seg == 3 ? WfcB : Wh2oB;
  float4 v = ((const float4*)src)[i];
  bf16x4 o = {(bf16_t)v.x, (bf16_t)v.y, (bf16_t)v.z, (bf16_t)v.w};
  *(bf16x4*)(dst + (size_t)i * 4) = o;
}

__global__ __launch_bounds__(256) void perm_cast_k(const float* __restrict__ src,
                                                   bf16_t* __restrict__ dst)
{
  const int i = blockIdx.x * 256 + threadIdx.x;
  const int pg = i >> 7, kq = (i & 127) << 2;
  const int g = pg / 48, rem = pg - g * 48, sec = rem >> 4, jj = rem & 15;
  const int srow = sec * 512 + g * 16 + jj;
  float4 v = *(const float4*)(src + (size_t)srow * DIN + kq);
  bf16x4 o = {(bf16_t)v.x, (bf16_t)v.y, (bf16_t)v.z, (bf16_t)v.w};
  *(bf16x4*)(dst + (size_t)pg * DIN + kq) = o;
}

__global__ void perm_bias_k(const float* __restrict__ bih, const float* __restrict__ bhh,
                            float* __restrict__ bihp, float* __restrict__ bhhp)
{
  const int pg = blockIdx.x * 256 + threadIdx.x;
  if (pg >= G3) return;
  const int g = pg / 48, rem = pg - g * 48, sec = rem >> 4, jj = rem & 15;
  const int srow = sec * 512 + g * 16 + jj;
  bihp[pg] = bih[srow];
  bhhp[pg] = bhh[srow];
}

__global__ void bcat_k(const float* __restrict__ a, const float* __restrict__ b,
                       const float* __restrict__ c, float* __restrict__ d)
{
  const int i = blockIdx.x * 256 + threadIdx.x;
  if (i >= G3) return;
  d[i] = i < 512 ? a[i] : (i < 1024 ? b[i - 512] : c[i - 1024]);
}

__global__ __launch_bounds__(256) void yemb_k(const int* __restrict__ y,
                                              const float* __restrict__ embW,
                                              bf16_t* __restrict__ out)
{
  const int idx = blockIdx.x * 256 + threadIdx.x;
  const int rb = idx >> 6, c = (idx & 63) << 3;
  const int tok = y[rb];
  const float4* s = (const float4*)(embW + (size_t)tok * DIN + c);
  float4 v0 = s[0], v1 = s[1];
  bf16x8 o = {(bf16_t)v0.x, (bf16_t)v0.y, (bf16_t)v0.z, (bf16_t)v0.w,
              (bf16_t)v1.x, (bf16_t)v1.y, (bf16_t)v1.z, (bf16_t)v1.w};
  *(bf16x8*)(out + (size_t)rb * DIN + c) = o;
}

__global__ __launch_bounds__(256) void ct_k(const float* __restrict__ ctx,
                                            const float* __restrict__ Watt,
                                            const float* __restrict__ batt,
                                            float* __restrict__ ct)
{
  const int idx = blockIdx.x * 256 + threadIdx.x;
  const int b = idx >> 9, j = idx & 511;
  const float4* c4 = (const float4*)(ctx + (size_t)b * FFEAT);
  const float4* w4 = (const float4*)(Watt + (size_t)j * FFEAT);
  float s = batt[j];
  for (int q = 0; q < FFEAT / 4; ++q) {
    float4 cc = c4[q], ww = w4[q];
    s += cc.x * ww.x + cc.y * ww.y + cc.z * ww.z + cc.w * ww.w;
  }
  ct[idx] = tanhf(s);
}

__global__ __launch_bounds__(256) void reduce_rows(const float* __restrict__ partial,
                                                   float* __restrict__ rowsum, int NB)
{
  const int wv = threadIdx.x >> 6, lane = threadIdx.x & 63;
  const int row = blockIdx.x * 4 + wv;
  float s = 0.f;
  for (int c = lane; c < NB; c += 64) s += partial[(size_t)row * NB + c];
  for (int m = 1; m < 64; m <<= 1) s += __shfl_xor(s, m);
  if (lane == 0) rowsum[row] = s;
}

__global__ __launch_bounds__(256) void normalize_k(const bf16_t* __restrict__ e,
                                                   const float* __restrict__ rowsum,
                                                   float* __restrict__ out)
{
  const int row = blockIdx.y;
  const int c8 = blockIdx.x * 256 + threadIdx.x;
  if (c8 >= VOCAB / 8) return;
  const float inv = 1.0f / rowsum[row];
  const size_t base = (size_t)row * VOCAB + (size_t)c8 * 8;
  bf16x8 v = *(const bf16x8*)(e + base);
  float4 o0 = {(float)v[0] * inv, (float)v[1] * inv, (float)v[2] * inv, (float)v[3] * inv};
  float4 o1 = {(float)v[4] * inv, (float)v[5] * inv, (float)v[6] * inv, (float)v[7] * inv};
  *(float4*)(out + base) = o0;
  *(float4*)(out + base + 4) = o1;
}

// ---------------------------------------------------------------------------
extern "C" void kernel_launch(void* const* d_in, const int* in_sizes, int n_in,
                              void* d_out, int out_size, void* d_ws, size_t ws_size,
                              hipStream_t stream)
{
  const int*   y     = (const int*)  d_in[0];
  const float* ctx   = (const float*)d_in[1];
  const float* embW  = (const float*)d_in[2];
  const float* W_ih  = (const float*)d_in[3];
  const float* b_ih  = (const float*)d_in[4];
  const float* W_hh  = (const float*)d_in[5];
  const float* b_hh  = (const float*)d_in[6];
  const float* W_att = (const float*)d_in[7];
  const float* b_att = (const float*)d_in[8];
  const float* Wq    = (const float*)d_in[9];
  const float* bq    = (const float*)d_in[10];
  const float* Wk    = (const float*)d_in[11];
  const float* bk    = (const float*)d_in[12];
  const float* Wv    = (const float*)d_in[13];
  const float* bv    = (const float*)d_in[14];
  const float* Wfc   = (const float*)d_in[15];
  const float* bfc   = (const float*)d_in[16];
  const float* Wh2o  = (const float*)d_in[17];
  const float* bh2o  = (const float*)d_in[18];
  const float* W_out = (const float*)d_in[19];
  const float* b_out = (const float*)d_in[20];

  char* p = (char*)d_ws;
  auto alloc = [&](size_t bytes) {
    char* r = p;
    p += (bytes + 255) & ~(size_t)255;
    return r;
  };
  bf16_t* WoutB   = (bf16_t*)alloc((size_t)VOCAB * DIN * 2);
  bf16_t* WgIh    = (bf16_t*)alloc((size_t)G3 * DIN * 2);
  bf16_t* WgHh    = (bf16_t*)alloc((size_t)G3 * DIN * 2);
  bf16_t* Wqkv    = (bf16_t*)alloc((size_t)G3 * DIN * 2);
  bf16_t* WfcB    = (bf16_t*)alloc((size_t)HID * HID * 2);
  bf16_t* Wh2oB   = (bf16_t*)alloc((size_t)HID * HID * 2);
  float*  bIhP    = (float*)alloc(G3 * 4);
  float*  bHhP    = (float*)alloc(G3 * 4);
  float*  bQkv    = (float*)alloc(G3 * 4);
  bf16_t* Yemb    = (bf16_t*)alloc((size_t)ROWS * DIN * 2);
  float*  giP     = (float*)alloc((size_t)ROWS * G3 * 4);
  float*  ctB     = (float*)alloc((size_t)BATCH * HID * 4);
  unsigned int* hbuf = (unsigned int*)alloc((size_t)2 * 16384 * 4);
  bf16_t* Xall    = (bf16_t*)alloc((size_t)ROWS * DIN * 2);
  bf16_t* QKV     = (bf16_t*)alloc((size_t)ROWS * G3 * 2);
  bf16_t* attO    = (bf16_t*)alloc((size_t)ROWS * HID * 2);
  bf16_t* h2B     = (bf16_t*)alloc((size_t)ROWS * HID * 2);
  bf16_t* logit   = (bf16_t*)alloc((size_t)ROWS * DIN * 2);
  float*  partial = (float*)alloc((size_t)ROWS * 125 * 4);
  float*  rowsum  = (float*)alloc((size_t)ROWS * 4);
  int*    flags   = (int*)alloc(32 * 4 * 64);
  bf16_t* eCache  = (bf16_t*)alloc((size_t)ROWS * VOCAB * 2);   // 131 MB

  hipMemsetAsync(hbuf, 0, (size_t)2 * 16384 * 4, stream);
  hipMemsetAsync(flags, 0, 32 * 4 * 64, stream);

  // weight prep (W_out cast fused into phaseA launch below)
  cast5_k<<<1280, 256, 0, stream>>>(Wq, Wk, Wv, Wfc, Wh2o, Wqkv, WfcB, Wh2oB);
  perm_cast_k<<<768, 256, 0, stream>>>(W_ih, WgIh);
  perm_cast_k<<<768, 256, 0, stream>>>(W_hh, WgHh);
  perm_bias_k<<<6, 256, 0, stream>>>(b_ih, b_hh, bIhP, bHhP);
  bcat_k<<<6, 256, 0, stream>>>(bq, bk, bv, bQkv);
  yemb_k<<<512, 256, 0, stream>>>(y, embW, Yemb);
  ct_k<<<128, 256, 0, stream>>>(ctx, W_att, b_att, ctB);

  // gi = Yemb @ WgIh^T + bIhP  (fp32)
  gemm_lds<EPI_F32, DIN><<<dim3(12, 16), 256, 0, stream>>>(
      Yemb, WgIh, bIhP, giP, ROWS, G3);

  // GRU recurrence (blocks 0-31) + W_out cast (blocks 32-223)
  phaseA_k<<<224, 256, 0, stream>>>(WgHh, bHhP, giP, ctB, hbuf, Xall, flags,
                                    W_out, WoutB);

  // QKV = X @ [Wq;Wk;Wv]^T + b
  gemm_lds<EPI_BF16, DIN><<<dim3(12, 16), 256, 0, stream>>>(
      Xall, Wqkv, bQkv, QKV, ROWS, G3);

  attn_k<<<512, 256, 0, stream>>>(QKV, attO);

  gemm_lds<EPI_BF16, HID><<<dim3(4, 16), 256, 0, stream>>>(
      attO, WfcB, bfc, h2B, ROWS, HID);

  gemm_lds<EPI_TANH, HID><<<dim3(4, 16), 256, 0, stream>>>(
      h2B, Wh2oB, bh2o, logit, ROWS, DIN);

  // vocab: single GEMM -> bf16 exp cache + partial sums (NB = 125)
  gemm_v<DIN><<<1000, 512, 0, stream>>>(
      logit, WoutB, b_out, eCache, partial, ROWS, VOCAB, 125);
  reduce_rows<<<512, 256, 0, stream>>>(partial, rowsum, 125);
  normalize_k<<<dim3(16, ROWS), 256, 0, stream>>>(eCache, rowsum, (float*)d_out);
}

// Round 11
// 440.161 us; speedup vs baseline: 1.1425x; 1.0346x over previous
//
#include <hip/hip_runtime.h>
#include <hip/hip_bf16.h>
#include <math.h>

typedef __bf16 bf16_t;
typedef __bf16 bf16x8 __attribute__((ext_vector_type(8)));
typedef __bf16 bf16x4 __attribute__((ext_vector_type(4)));
typedef float  f32x4  __attribute__((ext_vector_type(4)));

#define T_STEPS 32
#define BATCH   64
#define DIN     512
#define HID     512
#define VOCAB   32000
#define FFEAT   768
#define ROWS    2048   /* T*B */
#define G3      1536   /* 3*H */
#define NBLK_A  32
#define NBLK_GI 192    /* gi-producer blocks in phaseA launch */

#define EPI_F32  0
#define EPI_BF16 1
#define EPI_TANH 2

#define GLOAD16(gp, lp) __builtin_amdgcn_global_load_lds( \
    (const __attribute__((address_space(1))) void*)(gp),  \
    (__attribute__((address_space(3))) void*)(lp), 16, 0, 0)

// ===========================================================================
// gemm_v: 256x256 VOCAB GEMM, barrier-minimized (R11).
// Same fragment mapping/swizzle as R10 (proven: 0 bank conflicts) but the
// schedule is 8 K-tiles of BK=64, each = [gate; barrier B0; stage; ph0; ph1;
// barrier B1; stage; ph2; ph3] -- 2 barriers/tile (17 total vs 65). Within a
// tile the 4 phases are straight-line (32 ds_read + 64 MFMA ILP window).
// Stage ledger (target tile X -> buf[X&1]):
//   X.Ah0     @ B1(X-2)   (buf.Ah0 dead after X-2's ph0-1)
//   X.Ah1,X.B @ B0(X-1)   (buf^1 regions dead at X-1 entry)
// Gate at B0(kt): loads issued before = ...,B0(kt-1):[kt.Ah1,kt.B x6],
// B1(kt-1):[kt+1.Ah0 x2] -> vmcnt(2) ensures tile kt landed (kt=0: vmcnt(8)
// after 16-load prologue; kt=NT-1: vmcnt(0), nothing staged after).
// ===========================================================================
#define PHASEQ(BUF, MH, KS)                                                   \
  {                                                                           \
    bf16x8 af_[4], bf_[4];                                                    \
    _Pragma("unroll")                                                         \
    for (int m2 = 0; m2 < 4; ++m2) {                                          \
      const int row = wm * 64 + m2 * 16 + la;                                 \
      const int sl = ((KS) * 4 + lg) ^ (row & 7);                             \
      af_[m2] =                                                               \
          *(const bf16x8*)&lds[((BUF)*4 + (MH)) * 8192 + row * 64 + sl * 8];  \
    }                                                                         \
    _Pragma("unroll")                                                         \
    for (int nj = 0; nj < 4; ++nj) {                                          \
      const int row = wn * 32 + (nj & 1) * 16 + la;                           \
      const int sl = ((KS) * 4 + lg) ^ (row & 7);                             \
      bf_[nj] =                                                               \
          *(const bf16x8*)&lds[((BUF)*4 + 2 + (nj >> 1)) * 8192 + row * 64 + sl * 8];\
    }                                                                         \
    __builtin_amdgcn_s_setprio(1);                                            \
    _Pragma("unroll")                                                         \
    for (int m2 = 0; m2 < 4; ++m2)                                            \
      _Pragma("unroll")                                                       \
      for (int nj = 0; nj < 4; ++nj)                                          \
        acc[(MH)*4 + m2][nj] =                                                \
            __builtin_amdgcn_mfma_f32_16x16x32_bf16(                          \
                af_[m2], bf_[nj], acc[(MH)*4 + m2][nj], 0, 0, 0);             \
    __builtin_amdgcn_s_setprio(0);                                            \
  }

template<int KD>
__global__ __launch_bounds__(512, 2) void gemm_v(
    const bf16_t* __restrict__ A, const bf16_t* __restrict__ B,
    const float* __restrict__ bias, bf16_t* __restrict__ ecache,
    float* __restrict__ partial, int M, int N, int NB)
{
  __shared__ bf16_t lds[2 * 4 * 8192];   // 128 KB
  __shared__ float psum[256][4];
  const int tid = threadIdx.x;
  const int lane = tid & 63, wv = tid >> 6;
  const int wm = wv >> 2, wn = wv & 3;
  const int la = lane & 15, lg = lane >> 4;

  // bn-major XCD-chunk swizzle (nwg = NB * M/256, multiple of 8)
  const int lin = blockIdx.x;
  const int mt = M >> 8;                       // 8
  const int cpx = (NB * mt) >> 3;
  const int wg = (lin & 7) * cpx + (lin >> 3);
  const int bn = wg / mt, bm = wg - bn * mt;

  auto stageA = [&](int buf, int h, int kt) {
    const size_t base = (size_t)(bm * 256 + h * 128) * KD + (size_t)kt * 64;
#pragma unroll
    for (int q = 0; q < 2; ++q) {
      const int L = q * 512 + tid;
      const int row = L >> 3, sl = L & 7;
      const int c = sl ^ (row & 7);
      GLOAD16(A + base + (size_t)row * KD + c * 8,
              &lds[(buf * 4 + h) * 8192 + L * 8]);
    }
  };
  auto stageB = [&](int buf, int h, int kt) {
    const size_t base = (size_t)(bn * 256 + h * 128) * KD + (size_t)kt * 64;
#pragma unroll
    for (int q = 0; q < 2; ++q) {
      const int L = q * 512 + tid;
      const int row = L >> 3, sl = L & 7;
      const int c = sl ^ (row & 7);
      GLOAD16(B + base + (size_t)row * KD + c * 8,
              &lds[(buf * 4 + 2 + h) * 8192 + L * 8]);
    }
  };

  f32x4 acc[8][4] = {};
  constexpr int NT = KD >> 6;                  // 8 for K=512

  // prologue: T0 + T1 fully staged (16 loads/thread)
  stageA(0, 0, 0); stageA(0, 1, 0); stageB(0, 0, 0); stageB(0, 1, 0);
  stageA(1, 0, 1); stageA(1, 1, 1); stageB(1, 0, 1); stageB(1, 1, 1);

#pragma unroll
  for (int kt = 0; kt < NT; ++kt) {
    const int buf = kt & 1;
    if (kt == 0) {
      asm volatile("s_waitcnt vmcnt(8)" ::: "memory");   // T0 landed
    } else if (kt == NT - 1) {
      asm volatile("s_waitcnt vmcnt(0)" ::: "memory");   // final drain
    } else {
      asm volatile("s_waitcnt vmcnt(2)" ::: "memory");   // tile kt landed
    }
    __builtin_amdgcn_s_barrier();                        // B0
    if (kt > 0 && kt + 1 < NT) {                         // stage (kt+1).Ah1+B
      stageA(buf ^ 1, 1, kt + 1);
      stageB(buf ^ 1, 0, kt + 1);
      stageB(buf ^ 1, 1, kt + 1);
    }
    PHASEQ(buf, 0, 0)
    PHASEQ(buf, 0, 1)
    __builtin_amdgcn_s_barrier();                        // B1
    if (kt + 2 < NT) stageA(buf, 0, kt + 2);             // stage (kt+2).Ah0
    PHASEQ(buf, 1, 0)
    PHASEQ(buf, 1, 1)
  }

  // ---- epilogue: e = exp(acc+bias) -> paired u32 stores + row sums --------
  float bv[4];
#pragma unroll
  for (int nj = 0; nj < 4; ++nj) {
    const int col = bn * 256 + (nj >> 1) * 128 + wn * 32 + (nj & 1) * 16 + la;
    bv[nj] = bias[col];
  }
  const int odd = la & 1;
#pragma unroll
  for (int mi = 0; mi < 8; ++mi) {
#pragma unroll
    for (int rr = 0; rr < 4; ++rr) {
      const int rowl = (mi >> 2) * 128 + wm * 64 + (mi & 3) * 16 + lg * 4 + rr;
      const int row = bm * 256 + rowl;
      float vsum = 0.f;
#pragma unroll
      for (int nj = 0; nj < 4; ++nj) {
        const float e = expf(acc[mi][nj][rr] + bv[nj]);
        vsum += e;
        const unsigned int mine =
            (unsigned int)__builtin_bit_cast(unsigned short, (bf16_t)e);
        const unsigned int other = (unsigned int)__shfl_xor((int)mine, 1);
        if (!odd) {
          const int col = bn * 256 + (nj >> 1) * 128 + wn * 32 + (nj & 1) * 16 + la;
          *(unsigned int*)&ecache[(size_t)row * N + col] = mine | (other << 16);
        }
      }
      vsum += __shfl_xor(vsum, 1);
      vsum += __shfl_xor(vsum, 2);
      vsum += __shfl_xor(vsum, 4);
      vsum += __shfl_xor(vsum, 8);
      if (la == 0) psum[rowl][wn] = vsum;
    }
  }
  __syncthreads();
  if (tid < 256) {
    partial[(size_t)(bm * 256 + tid) * NB + bn] =
        psum[tid][0] + psum[tid][1] + psum[tid][2] + psum[tid][3];
  }
}

// ---------------------------------------------------------------------------
// 128x128 LDS GEMM (R6 pipeline, K templated) for QKV/fc/h2o.
// ---------------------------------------------------------------------------
template<int EPI, int KD>
__global__ __launch_bounds__(256) void gemm_lds(
    const bf16_t* __restrict__ A, const bf16_t* __restrict__ B,
    const float* __restrict__ bias, void* __restrict__ out, int M, int N)
{
  __shared__ bf16_t As[3][128 * 32];
  __shared__ bf16_t Bs[3][128 * 32];

  const int lane = threadIdx.x & 63;
  const int wv   = threadIdx.x >> 6;
  const int wm = wv >> 1, wn = wv & 1;
  const int bn = blockIdx.x, bm = blockIdx.y;
  const int la = lane & 15, lg = lane >> 4;
  const int tid = threadIdx.x;

  auto stage = [&](int buf, int k0) {
#pragma unroll
    for (int q = 0; q < 2; ++q) {
      const int idx = q * 256 + tid;
      const int row = idx >> 2, c = idx & 3;
      const int gch = c ^ ((row >> 1) & 3);
      GLOAD16(A + (size_t)(bm * 128 + row) * KD + k0 + gch * 8, &As[buf][idx * 8]);
      GLOAD16(B + (size_t)(bn * 128 + row) * KD + k0 + gch * 8, &Bs[buf][idx * 8]);
    }
  };
  const int rdch = (lg ^ ((la >> 1) & 3)) * 8;

  f32x4 acc[4][4] = {};
  constexpr int NT = KD >> 5;
  stage(0, 0);
  stage(1, 32);
  for (int kt = 0; kt < NT; ++kt) {
    if (kt + 1 < NT) {
      asm volatile("s_waitcnt vmcnt(4)" ::: "memory");
    } else {
      asm volatile("s_waitcnt vmcnt(0)" ::: "memory");
    }
    __builtin_amdgcn_s_barrier();
    __builtin_amdgcn_sched_barrier(0);
    if (kt + 2 < NT) stage((kt + 2) % 3, (kt + 2) * 32);
    const bf16_t* Ab = As[kt % 3];
    const bf16_t* Bb = Bs[kt % 3];
    bf16x8 a[4], b[4];
#pragma unroll
    for (int i = 0; i < 4; ++i)
      a[i] = *(const bf16x8*)(Ab + (wm * 64 + i * 16 + la) * 32 + rdch);
#pragma unroll
    for (int j = 0; j < 4; ++j)
      b[j] = *(const bf16x8*)(Bb + (wn * 64 + j * 16 + la) * 32 + rdch);
    __builtin_amdgcn_s_setprio(1);
#pragma unroll
    for (int i = 0; i < 4; ++i)
#pragma unroll
      for (int j = 0; j < 4; ++j)
        acc[i][j] = __builtin_amdgcn_mfma_f32_16x16x32_bf16(a[i], b[j], acc[i][j], 0, 0, 0);
    __builtin_amdgcn_s_setprio(0);
  }

  const int m0 = bm * 128 + wm * 64;
  const int n0 = bn * 128 + wn * 64;
  float bv4[4];
#pragma unroll
  for (int j = 0; j < 4; ++j) bv4[j] = bias[n0 + j * 16 + la];
#pragma unroll
  for (int i = 0; i < 4; ++i) {
#pragma unroll
    for (int r = 0; r < 4; ++r) {
      const int row = m0 + i * 16 + lg * 4 + r;
#pragma unroll
      for (int j = 0; j < 4; ++j) {
        const int col = n0 + j * 16 + la;
        float v = acc[i][j][r] + bv4[j];
        if constexpr (EPI == EPI_F32) {
          ((float*)out)[(size_t)row * N + col] = v;
        } else if constexpr (EPI == EPI_BF16) {
          ((bf16_t*)out)[(size_t)row * N + col] = (bf16_t)v;
        } else {
          ((bf16_t*)out)[(size_t)row * N + col] = (bf16_t)tanhf(v);
        }
      }
    }
  }
}

// ---------------------------------------------------------------------------
// Phase A mega-launch (224 blocks):
//   blocks 0..31   : GRU recurrence (unchanged structure)
//   blocks 32..223 : gi-producer -- each computes ONE 128x128 tile of
//     gi = Yemb @ WgIh^T + bIhP (192 tiles = 16 bm x 12 bn), stores via
//     AGENT-scope atomic u32 (write-through to L3; same coherence pattern
//     as the proven h-exchange), bumps giflag[bm]; then grid-strides the
//     W_out f32->bf16 cast. Consumers poll giflag[t>>1]==12 per even step.
// ---------------------------------------------------------------------------
__global__ __launch_bounds__(256) void phaseA_k(
    const bf16_t* __restrict__ Wg, const float* __restrict__ bhh,
    float* __restrict__ gi, const float* __restrict__ ct,
    unsigned int* __restrict__ hbuf, bf16_t* __restrict__ Xall,
    int* __restrict__ flags, const float* __restrict__ Wout_f32,
    bf16_t* __restrict__ WoutB, const bf16_t* __restrict__ Yemb,
    const bf16_t* __restrict__ WgIh, const float* __restrict__ bIhP)
{
  __shared__ bf16_t Wl[48 * 520];
  __shared__ float bl[48];
  __shared__ bf16_t As2[3][128 * 32];
  __shared__ bf16_t Bs2[3][128 * 32];
  const int tid = threadIdx.x, blk = blockIdx.x;

  if (blk >= NBLK_A) {                          // ---- gi producer + cast ----
    const int s = blk - NBLK_A;                 // 0..191
    const int bm = s / 12, bn = s - bm * 12;
    const int lane = tid & 63, wv = tid >> 6;
    const int wm = wv >> 1, wn = wv & 1;
    const int la = lane & 15, lg = lane >> 4;

    auto stage = [&](int buf, int k0) {
#pragma unroll
      for (int q = 0; q < 2; ++q) {
        const int idx = q * 256 + tid;
        const int row = idx >> 2, c = idx & 3;
        const int gch = c ^ ((row >> 1) & 3);
        GLOAD16(Yemb + (size_t)(bm * 128 + row) * DIN + k0 + gch * 8, &As2[buf][idx * 8]);
        GLOAD16(WgIh + (size_t)(bn * 128 + row) * DIN + k0 + gch * 8, &Bs2[buf][idx * 8]);
      }
    };
    const int rdch = (lg ^ ((la >> 1) & 3)) * 8;
    f32x4 acc[4][4] = {};
    stage(0, 0);
    stage(1, 32);
    for (int kt = 0; kt < 16; ++kt) {
      if (kt + 1 < 16) { asm volatile("s_waitcnt vmcnt(4)" ::: "memory"); }
      else             { asm volatile("s_waitcnt vmcnt(0)" ::: "memory"); }
      __builtin_amdgcn_s_barrier();
      __builtin_amdgcn_sched_barrier(0);
      if (kt + 2 < 16) stage((kt + 2) % 3, (kt + 2) * 32);
      const bf16_t* Ab = As2[kt % 3];
      const bf16_t* Bb = Bs2[kt % 3];
      bf16x8 a[4], b[4];
#pragma unroll
      for (int i = 0; i < 4; ++i)
        a[i] = *(const bf16x8*)(Ab + (wm * 64 + i * 16 + la) * 32 + rdch);
#pragma unroll
      for (int j = 0; j < 4; ++j)
        b[j] = *(const bf16x8*)(Bb + (wn * 64 + j * 16 + la) * 32 + rdch);
      __builtin_amdgcn_s_setprio(1);
#pragma unroll
      for (int i = 0; i < 4; ++i)
#pragma unroll
        for (int j = 0; j < 4; ++j)
          acc[i][j] = __builtin_amdgcn_mfma_f32_16x16x32_bf16(a[i], b[j], acc[i][j], 0, 0, 0);
      __builtin_amdgcn_s_setprio(0);
    }
    const int m0 = bm * 128 + wm * 64;
    const int n0 = bn * 128 + wn * 64;
    float bv4[4];
#pragma unroll
    for (int j = 0; j < 4; ++j) bv4[j] = bIhP[n0 + j * 16 + la];
#pragma unroll
    for (int i = 0; i < 4; ++i) {
#pragma unroll
      for (int r = 0; r < 4; ++r) {
        const int row = m0 + i * 16 + lg * 4 + r;
#pragma unroll
        for (int j = 0; j < 4; ++j) {
          const int col = n0 + j * 16 + la;
          const float v = acc[i][j][r] + bv4[j];
          __hip_atomic_store((unsigned int*)&gi[(size_t)row * G3 + col],
                             __builtin_bit_cast(unsigned int, v),
                             __ATOMIC_RELAXED, __HIP_MEMORY_SCOPE_AGENT);
        }
      }
    }
    asm volatile("s_waitcnt vmcnt(0)" ::: "memory");
    __syncthreads();
    if (tid == 0) {
      __hip_atomic_fetch_add(&flags[2048 + bm * 16], 1, __ATOMIC_RELAXED,
                             __HIP_MEMORY_SCOPE_AGENT);
    }
    // W_out cast (grid-stride over the 192 producer blocks)
    const int n4 = VOCAB * DIN / 4;
    for (int i = s * 256 + tid; i < n4; i += NBLK_GI * 256) {
      float4 v = ((const float4*)Wout_f32)[i];
      bf16x4 o = {(bf16_t)v.x, (bf16_t)v.y, (bf16_t)v.z, (bf16_t)v.w};
      *(bf16x4*)(WoutB + (size_t)i * 4) = o;
    }
    return;
  }

  // ---- GRU recurrence (blocks 0..31) ----
  for (int i = tid; i < 48 * 64; i += 256) {
    const int rw = i >> 6, ch = (i & 63) << 3;
    *(bf16x8*)(Wl + rw * 520 + ch) = *(const bf16x8*)(Wg + (size_t)(blk * 48 + rw) * 512 + ch);
  }
  if (tid < 48) bl[tid] = bhh[blk * 48 + tid];
  __syncthreads();

  const int lane = tid & 63, wv = tid >> 6;
  const int la = lane & 15, lg = lane >> 4;
  const int jcol = blk * 16 + la;
  const int rowA = wv * 16 + la;

  const float blr = bl[la], blz = bl[16 + la], bln = bl[32 + la];
  float hprev[4], ctv[4];
#pragma unroll
  for (int r = 0; r < 4; ++r) {
    hprev[r] = 0.f;
    ctv[r] = ct[(size_t)(wv * 16 + lg * 4 + r) * HID + jcol];
  }

  for (int t = 0; t < T_STEPS; ++t) {
    // gi tile readiness (12 producer blocks per 2-step row band)
    if ((t & 1) == 0) {
      while (__hip_atomic_load(&flags[2048 + (t >> 1) * 16], __ATOMIC_RELAXED,
                               __HIP_MEMORY_SCOPE_AGENT) < 12) { }
      asm volatile("" ::: "memory");
    }
    const float* girow = gi + (size_t)t * BATCH * G3 + (size_t)blk * 48;
    float gv[12];
#pragma unroll
    for (int r = 0; r < 4; ++r) {
      const float* gp = girow + (size_t)(wv * 16 + lg * 4 + r) * G3;
      gv[r * 3 + 0] = gp[la];
      gv[r * 3 + 1] = gp[16 + la];
      gv[r * 3 + 2] = gp[32 + la];
    }
    if (t > 0) {
      if (lane < 32) {
        while (__hip_atomic_load(&flags[(lane * 4 + wv) * 16], __ATOMIC_RELAXED,
                                 __HIP_MEMORY_SCOPE_AGENT) < t) { }
      }
      asm volatile("" ::: "memory");
    }
    const unsigned long long* hb =
        (const unsigned long long*)(hbuf + (size_t)(t & 1) * 16384);
    bf16x8 af[16];
#pragma unroll
    for (int q = 0; q < 16; ++q) {
      union { unsigned long long u[2]; bf16x8 v; } c;
      const size_t bidx = (size_t)(2 * q + (lg >> 1)) * 256 + rowA * 4 + (lg & 1) * 2;
      c.u[0] = __hip_atomic_load(hb + bidx,     __ATOMIC_RELAXED, __HIP_MEMORY_SCOPE_AGENT);
      c.u[1] = __hip_atomic_load(hb + bidx + 1, __ATOMIC_RELAXED, __HIP_MEMORY_SCOPE_AGENT);
      af[q] = c.v;
    }
    f32x4 acc0 = {}, acc1 = {}, acc2 = {};
#pragma unroll
    for (int q = 0; q < 16; ++q) {
      const bf16_t* wp = Wl + q * 32 + lg * 8;
      bf16x8 b0 = *(const bf16x8*)(wp + (0 * 16 + la) * 520);
      bf16x8 b1 = *(const bf16x8*)(wp + (1 * 16 + la) * 520);
      bf16x8 b2 = *(const bf16x8*)(wp + (2 * 16 + la) * 520);
      acc0 = __builtin_amdgcn_mfma_f32_16x16x32_bf16(af[q], b0, acc0, 0, 0, 0);
      acc1 = __builtin_amdgcn_mfma_f32_16x16x32_bf16(af[q], b1, acc1, 0, 0, 0);
      acc2 = __builtin_amdgcn_mfma_f32_16x16x32_bf16(af[q], b2, acc2, 0, 0, 0);
    }
    float h1v[4];
#pragma unroll
    for (int r = 0; r < 4; ++r) {
      const float ghr = acc0[r] + blr;
      const float ghz = acc1[r] + blz;
      const float ghn = acc2[r] + bln;
      const float rr = 1.f / (1.f + expf(-(gv[r * 3 + 0] + ghr)));
      const float zz = 1.f / (1.f + expf(-(gv[r * 3 + 1] + ghz)));
      const float nn = tanhf(gv[r * 3 + 2] + rr * ghn);
      h1v[r] = (1.f - zz) * nn + zz * hprev[r];
      hprev[r] = h1v[r];
    }
    unsigned int* hn = hbuf + (size_t)((t + 1) & 1) * 16384 + blk * 512;
#pragma unroll
    for (int r = 0; r < 4; ++r) {
      const int row = wv * 16 + lg * 4 + r;
      const unsigned int mine =
          (unsigned int)__builtin_bit_cast(unsigned short, (bf16_t)h1v[r]);
      const unsigned int other = (unsigned int)__shfl_xor((int)mine, 1);
      if ((la & 1) == 0) {
        __hip_atomic_store(hn + row * 8 + (la >> 1), mine | (other << 16),
                           __ATOMIC_RELAXED, __HIP_MEMORY_SCOPE_AGENT);
      }
    }
    asm volatile("s_waitcnt vmcnt(0)" ::: "memory");
    if (lane == 0) {
      __hip_atomic_store(&flags[(blk * 4 + wv) * 16], t + 1, __ATOMIC_RELAXED,
                         __HIP_MEMORY_SCOPE_AGENT);
    }
#pragma unroll
    for (int r = 0; r < 4; ++r) {
      const int row = wv * 16 + lg * 4 + r;
      Xall[((size_t)t * BATCH + row) * HID + jcol] = (bf16_t)(h1v[r] * ctv[r]);
    }
  }
}

// ---------------------------------------------------------------------------
__global__ __launch_bounds__(256) void attn_k(const bf16_t* __restrict__ QKV,
                                              bf16_t* __restrict__ attO)
{
  __shared__ float sq[4][512], sk[4][512], sv[4][512], sw[4][64];
  const int tid = threadIdx.x;
  const int wv = tid >> 6, lane = tid & 63;
  const int row = blockIdx.x * 4 + wv;
  const bf16_t* base = QKV + (size_t)row * G3;
  bf16x8 vq = *(const bf16x8*)(base + lane * 8);
  bf16x8 vk = *(const bf16x8*)(base + 512 + lane * 8);
  bf16x8 vv = *(const bf16x8*)(base + 1024 + lane * 8);
#pragma unroll
  for (int e = 0; e < 8; ++e) {
    sq[wv][lane * 8 + e] = (float)vq[e];
    sk[wv][lane * 8 + e] = (float)vk[e];
    sv[wv][lane * 8 + e] = (float)vv[e];
  }
  __syncthreads();
  const int h = lane >> 3, g = lane & 7;
  float s = 0.f;
#pragma unroll 16
  for (int d = 0; d < 64; ++d) s += sq[wv][h * 64 + d] * sk[wv][g * 64 + d];
  s *= (1.f / 64.f);
  float m = s;
  m = fmaxf(m, __shfl_xor(m, 1));
  m = fmaxf(m, __shfl_xor(m, 2));
  m = fmaxf(m, __shfl_xor(m, 4));
  const float e = expf(s - m);
  float sum = e;
  sum += __shfl_xor(sum, 1);
  sum += __shfl_xor(sum, 2);
  sum += __shfl_xor(sum, 4);
  sw[wv][lane] = e / sum;
  __syncthreads();
#pragma unroll
  for (int rep = 0; rep < 8; ++rep) {
    const int idx = rep * 64 + lane;
    const int hh = idx >> 6, d = idx & 63;
    float o = 0.f;
#pragma unroll
    for (int gg = 0; gg < 8; ++gg) o += sw[wv][hh * 8 + gg] * sv[wv][gg * 64 + d];
    attO[(size_t)row * HID + idx] = (bf16_t)o;
  }
}

// --------------------------- small prep kernels ----------------------------
__global__ __launch_bounds__(256) void cast5_k(
    const float* __restrict__ s0, const float* __restrict__ s1,
    const float* __restrict__ s2, const float* __restrict__ s3,
    const float* __restrict__ s4, bf16_t* __restrict__ Wqkv,
    bf16_t* __restrict__ WfcB, bf16_t* __restrict__ Wh2oB)
{
  const int seg = blockIdx.x >> 8;
  const int i = (blockIdx.x & 255) * 256 + threadIdx.x;
  const float* src = seg == 0 ? s0 : seg == 1 ? s1 : seg == 2 ? s2
                   : seg == 3 ? s3 : s4;
  bf16_t* dst = seg <= 2 ? Wqkv + (size_t)seg * HID * DIN
              : seg == 3 ? WfcB : Wh2oB;
  float4 v = ((const float4*)src)[i];
  bf16x4 o = {(bf16_t)v.x, (bf16_t)v.y, (bf16_t)v.z, (bf16_t)v.w};
  *(bf16x4*)(dst + (size_t)i * 4) = o;
}

__global__ __launch_bounds__(256) void perm_cast_k(const float* __restrict__ src,
                                                   bf16_t* __restrict__ dst)
{
  const int i = blockIdx.x * 256 + threadIdx.x;
  const int pg = i >> 7, kq = (i & 127) << 2;
  const int g = pg / 48, rem = pg - g * 48, sec = rem >> 4, jj = rem & 15;
  const int srow = sec * 512 + g * 16 + jj;
  float4 v = *(const float4*)(src + (size_t)srow * DIN + kq);
  bf16x4 o = {(bf16_t)v.x, (bf16_t)v.y, (bf16_t)v.z, (bf16_t)v.w};
  *(bf16x4*)(dst + (size_t)pg * DIN + kq) = o;
}

__global__ void perm_bias_k(const float* __restrict__ bih, const float* __restrict__ bhh,
                            float* __restrict__ bihp, float* __restrict__ bhhp)
{
  const int pg = blockIdx.x * 256 + threadIdx.x;
  if (pg >= G3) return;
  const int g = pg / 48, rem = pg - g * 48, sec = rem >> 4, jj = rem & 15;
  const int srow = sec * 512 + g * 16 + jj;
  bihp[pg] = bih[srow];
  bhhp[pg] = bhh[srow];
}

__global__ void bcat_k(const float* __restrict__ a, const float* __restrict__ b,
                       const float* __restrict__ c, float* __restrict__ d)
{
  const int i = blockIdx.x * 256 + threadIdx.x;
  if (i >= G3) return;
  d[i] = i < 512 ? a[i] : (i < 1024 ? b[i - 512] : c[i - 1024]);
}

__global__ __launch_bounds__(256) void yemb_k(const int* __restrict__ y,
                                              const float* __restrict__ embW,
                                              bf16_t* __restrict__ out)
{
  const int idx = blockIdx.x * 256 + threadIdx.x;
  const int rb = idx >> 6, c = (idx & 63) << 3;
  const int tok = y[rb];
  const float4* s = (const float4*)(embW + (size_t)tok * DIN + c);
  float4 v0 = s[0], v1 = s[1];
  bf16x8 o = {(bf16_t)v0.x, (bf16_t)v0.y, (bf16_t)v0.z, (bf16_t)v0.w,
              (bf16_t)v1.x, (bf16_t)v1.y, (bf16_t)v1.z, (bf16_t)v1.w};
  *(bf16x8*)(out + (size_t)rb * DIN + c) = o;
}

__global__ __launch_bounds__(256) void ct_k(const float* __restrict__ ctx,
                                            const float* __restrict__ Watt,
                                            const float* __restrict__ batt,
                                            float* __restrict__ ct)
{
  const int idx = blockIdx.x * 256 + threadIdx.x;
  const int b = idx >> 9, j = idx & 511;
  const float4* c4 = (const float4*)(ctx + (size_t)b * FFEAT);
  const float4* w4 = (const float4*)(Watt + (size_t)j * FFEAT);
  float s = batt[j];
  for (int q = 0; q < FFEAT / 4; ++q) {
    float4 cc = c4[q], ww = w4[q];
    s += cc.x * ww.x + cc.y * ww.y + cc.z * ww.z + cc.w * ww.w;
  }
  ct[idx] = tanhf(s);
}

__global__ __launch_bounds__(256) void reduce_rows(const float* __restrict__ partial,
                                                   float* __restrict__ rowsum, int NB)
{
  const int wv = threadIdx.x >> 6, lane = threadIdx.x & 63;
  const int row = blockIdx.x * 4 + wv;
  float s = 0.f;
  for (int c = lane; c < NB; c += 64) s += partial[(size_t)row * NB + c];
  for (int m = 1; m < 64; m <<= 1) s += __shfl_xor(s, m);
  if (lane == 0) rowsum[row] = s;
}

__global__ __launch_bounds__(256) void normalize_k(const bf16_t* __restrict__ e,
                                                   const float* __restrict__ rowsum,
                                                   float* __restrict__ out)
{
  const int row = blockIdx.y;
  const int c8 = blockIdx.x * 256 + threadIdx.x;
  if (c8 >= VOCAB / 8) return;
  const float inv = 1.0f / rowsum[row];
  const size_t base = (size_t)row * VOCAB + (size_t)c8 * 8;
  bf16x8 v = *(const bf16x8*)(e + base);
  float4 o0 = {(float)v[0] * inv, (float)v[1] * inv, (float)v[2] * inv, (float)v[3] * inv};
  float4 o1 = {(float)v[4] * inv, (float)v[5] * inv, (float)v[6] * inv, (float)v[7] * inv};
  *(float4*)(out + base) = o0;
  *(float4*)(out + base + 4) = o1;
}

// ---------------------------------------------------------------------------
extern "C" void kernel_launch(void* const* d_in, const int* in_sizes, int n_in,
                              void* d_out, int out_size, void* d_ws, size_t ws_size,
                              hipStream_t stream)
{
  const int*   y     = (const int*)  d_in[0];
  const float* ctx   = (const float*)d_in[1];
  const float* embW  = (const float*)d_in[2];
  const float* W_ih  = (const float*)d_in[3];
  const float* b_ih  = (const float*)d_in[4];
  const float* W_hh  = (const float*)d_in[5];
  const float* b_hh  = (const float*)d_in[6];
  const float* W_att = (const float*)d_in[7];
  const float* b_att = (const float*)d_in[8];
  const float* Wq    = (const float*)d_in[9];
  const float* bq    = (const float*)d_in[10];
  const float* Wk    = (const float*)d_in[11];
  const float* bk    = (const float*)d_in[12];
  const float* Wv    = (const float*)d_in[13];
  const float* bv    = (const float*)d_in[14];
  const float* Wfc   = (const float*)d_in[15];
  const float* bfc   = (const float*)d_in[16];
  const float* Wh2o  = (const float*)d_in[17];
  const float* bh2o  = (const float*)d_in[18];
  const float* W_out = (const float*)d_in[19];
  const float* b_out = (const float*)d_in[20];

  char* p = (char*)d_ws;
  auto alloc = [&](size_t bytes) {
    char* r = p;
    p += (bytes + 255) & ~(size_t)255;
    return r;
  };
  bf16_t* WoutB   = (bf16_t*)alloc((size_t)VOCAB * DIN * 2);
  bf16_t* WgIh    = (bf16_t*)alloc((size_t)G3 * DIN * 2);
  bf16_t* WgHh    = (bf16_t*)alloc((size_t)G3 * DIN * 2);
  bf16_t* Wqkv    = (bf16_t*)alloc((size_t)G3 * DIN * 2);
  bf16_t* WfcB    = (bf16_t*)alloc((size_t)HID * HID * 2);
  bf16_t* Wh2oB   = (bf16_t*)alloc((size_t)HID * HID * 2);
  float*  bIhP    = (float*)alloc(G3 * 4);
  float*  bHhP    = (float*)alloc(G3 * 4);
  float*  bQkv    = (float*)alloc(G3 * 4);
  bf16_t* Yemb    = (bf16_t*)alloc((size_t)ROWS * DIN * 2);
  float*  giP     = (float*)alloc((size_t)ROWS * G3 * 4);
  float*  ctB     = (float*)alloc((size_t)BATCH * HID * 4);
  unsigned int* hbuf = (unsigned int*)alloc((size_t)2 * 16384 * 4);
  bf16_t* Xall    = (bf16_t*)alloc((size_t)ROWS * DIN * 2);
  bf16_t* QKV     = (bf16_t*)alloc((size_t)ROWS * G3 * 2);
  bf16_t* attO    = (bf16_t*)alloc((size_t)ROWS * HID * 2);
  bf16_t* h2B     = (bf16_t*)alloc((size_t)ROWS * HID * 2);
  bf16_t* logit   = (bf16_t*)alloc((size_t)ROWS * DIN * 2);
  float*  partial = (float*)alloc((size_t)ROWS * 125 * 4);
  float*  rowsum  = (float*)alloc((size_t)ROWS * 4);
  int*    flags   = (int*)alloc(16384);        // h-flags [0,8K) + gi-flags [8K,9K)
  bf16_t* eCache  = (bf16_t*)alloc((size_t)ROWS * VOCAB * 2);   // 131 MB

  hipMemsetAsync(hbuf, 0, (size_t)2 * 16384 * 4, stream);
  hipMemsetAsync(flags, 0, 16384, stream);

  // weight prep (gi-GEMM + W_out cast fused into phaseA launch below)
  cast5_k<<<1280, 256, 0, stream>>>(Wq, Wk, Wv, Wfc, Wh2o, Wqkv, WfcB, Wh2oB);
  perm_cast_k<<<768, 256, 0, stream>>>(W_ih, WgIh);
  perm_cast_k<<<768, 256, 0, stream>>>(W_hh, WgHh);
  perm_bias_k<<<6, 256, 0, stream>>>(b_ih, b_hh, bIhP, bHhP);
  bcat_k<<<6, 256, 0, stream>>>(bq, bk, bv, bQkv);
  yemb_k<<<512, 256, 0, stream>>>(y, embW, Yemb);
  ct_k<<<128, 256, 0, stream>>>(ctx, W_att, b_att, ctB);

  // GRU recurrence (0-31) + gi producers (32-223, then W_out cast)
  phaseA_k<<<NBLK_A + NBLK_GI, 256, 0, stream>>>(
      WgHh, bHhP, giP, ctB, hbuf, Xall, flags, W_out, WoutB, Yemb, WgIh, bIhP);

  // QKV = X @ [Wq;Wk;Wv]^T + b
  gemm_lds<EPI_BF16, DIN><<<dim3(12, 16), 256, 0, stream>>>(
      Xall, Wqkv, bQkv, QKV, ROWS, G3);

  attn_k<<<512, 256, 0, stream>>>(QKV, attO);

  gemm_lds<EPI_BF16, HID><<<dim3(4, 16), 256, 0, stream>>>(
      attO, WfcB, bfc, h2B, ROWS, HID);

  gemm_lds<EPI_TANH, HID><<<dim3(4, 16), 256, 0, stream>>>(
      h2B, Wh2oB, bh2o, logit, ROWS, DIN);

  // vocab: single GEMM -> bf16 exp cache + partial sums (NB = 125)
  gemm_v<DIN><<<1000, 512, 0, stream>>>(
      logit, WoutB, b_out, eCache, partial, ROWS, VOCAB, 125);
  reduce_rows<<<512, 256, 0, stream>>>(partial, rowsum, 125);
  normalize_k<<<dim3(16, ROWS), 256, 0, stream>>>(eCache, rowsum, (float*)d_out);
}

// Round 12
// 439.504 us; speedup vs baseline: 1.1442x; 1.0015x over previous
//
#include <hip/hip_runtime.h>
#include <hip/hip_bf16.h>
#include <math.h>

typedef __bf16 bf16_t;
typedef __bf16 bf16x8 __attribute__((ext_vector_type(8)));
typedef __bf16 bf16x4 __attribute__((ext_vector_type(4)));
typedef float  f32x4  __attribute__((ext_vector_type(4)));

#define T_STEPS 32
#define BATCH   64
#define DIN     512
#define HID     512
#define VOCAB   32000
#define FFEAT   768
#define ROWS    2048   /* T*B */
#define G3      1536   /* 3*H */
#define NBLK_A  32
#define NBLK_GI 192    /* gi-producer blocks in phaseA launch */

#define EPI_F32  0
#define EPI_BF16 1
#define EPI_TANH 2

#define GLOAD16(gp, lp) __builtin_amdgcn_global_load_lds( \
    (const __attribute__((address_space(1))) void*)(gp),  \
    (__attribute__((address_space(3))) void*)(lp), 16, 0, 0)

// ===========================================================================
// gemm_v: 256x256 VOCAB GEMM, barrier-minimized (R11).
// Same fragment mapping/swizzle as R10 (proven: 0 bank conflicts) but the
// schedule is 8 K-tiles of BK=64, each = [gate; barrier B0; stage; ph0; ph1;
// barrier B1; stage; ph2; ph3] -- 2 barriers/tile (17 total vs 65). Within a
// tile the 4 phases are straight-line (32 ds_read + 64 MFMA ILP window).
// Stage ledger (target tile X -> buf[X&1]):
//   X.Ah0     @ B1(X-2)   (buf.Ah0 dead after X-2's ph0-1)
//   X.Ah1,X.B @ B0(X-1)   (buf^1 regions dead at X-1 entry)
// Gate at B0(kt): loads issued before = ...,B0(kt-1):[kt.Ah1,kt.B x6],
// B1(kt-1):[kt+1.Ah0 x2] -> vmcnt(2) ensures tile kt landed (kt=0: vmcnt(8)
// after 16-load prologue; kt=NT-1: vmcnt(0), nothing staged after).
// ===========================================================================
#define PHASEQ(BUF, MH, KS)                                                   \
  {                                                                           \
    bf16x8 af_[4], bf_[4];                                                    \
    _Pragma("unroll")                                                         \
    for (int m2 = 0; m2 < 4; ++m2) {                                          \
      const int row = wm * 64 + m2 * 16 + la;                                 \
      const int sl = ((KS) * 4 + lg) ^ (row & 7);                             \
      af_[m2] =                                                               \
          *(const bf16x8*)&lds[((BUF)*4 + (MH)) * 8192 + row * 64 + sl * 8];  \
    }                                                                         \
    _Pragma("unroll")                                                         \
    for (int nj = 0; nj < 4; ++nj) {                                          \
      const int row = wn * 32 + (nj & 1) * 16 + la;                           \
      const int sl = ((KS) * 4 + lg) ^ (row & 7);                             \
      bf_[nj] =                                                               \
          *(const bf16x8*)&lds[((BUF)*4 + 2 + (nj >> 1)) * 8192 + row * 64 + sl * 8];\
    }                                                                         \
    __builtin_amdgcn_s_setprio(1);                                            \
    _Pragma("unroll")                                                         \
    for (int m2 = 0; m2 < 4; ++m2)                                            \
      _Pragma("unroll")                                                       \
      for (int nj = 0; nj < 4; ++nj)                                          \
        acc[(MH)*4 + m2][nj] =                                                \
            __builtin_amdgcn_mfma_f32_16x16x32_bf16(                          \
                af_[m2], bf_[nj], acc[(MH)*4 + m2][nj], 0, 0, 0);             \
    __builtin_amdgcn_s_setprio(0);                                            \
  }

template<int KD>
__global__ __launch_bounds__(512, 2) void gemm_v(
    const bf16_t* __restrict__ A, const bf16_t* __restrict__ B,
    const float* __restrict__ bias, bf16_t* __restrict__ ecache,
    float* __restrict__ partial, int M, int N, int NB)
{
  __shared__ bf16_t lds[2 * 4 * 8192];   // 128 KB
  __shared__ float psum[256][4];
  const int tid = threadIdx.x;
  const int lane = tid & 63, wv = tid >> 6;
  const int wm = wv >> 2, wn = wv & 3;
  const int la = lane & 15, lg = lane >> 4;

  // bn-major XCD-chunk swizzle (nwg = NB * M/256, multiple of 8)
  const int lin = blockIdx.x;
  const int mt = M >> 8;                       // 8
  const int cpx = (NB * mt) >> 3;
  const int wg = (lin & 7) * cpx + (lin >> 3);
  const int bn = wg / mt, bm = wg - bn * mt;

  auto stageA = [&](int buf, int h, int kt) {
    const size_t base = (size_t)(bm * 256 + h * 128) * KD + (size_t)kt * 64;
#pragma unroll
    for (int q = 0; q < 2; ++q) {
      const int L = q * 512 + tid;
      const int row = L >> 3, sl = L & 7;
      const int c = sl ^ (row & 7);
      GLOAD16(A + base + (size_t)row * KD + c * 8,
              &lds[(buf * 4 + h) * 8192 + L * 8]);
    }
  };
  auto stageB = [&](int buf, int h, int kt) {
    const size_t base = (size_t)(bn * 256 + h * 128) * KD + (size_t)kt * 64;
#pragma unroll
    for (int q = 0; q < 2; ++q) {
      const int L = q * 512 + tid;
      const int row = L >> 3, sl = L & 7;
      const int c = sl ^ (row & 7);
      GLOAD16(B + base + (size_t)row * KD + c * 8,
              &lds[(buf * 4 + 2 + h) * 8192 + L * 8]);
    }
  };

  f32x4 acc[8][4] = {};
  constexpr int NT = KD >> 6;                  // 8 for K=512

  // prologue: T0 + T1 fully staged (16 loads/thread)
  stageA(0, 0, 0); stageA(0, 1, 0); stageB(0, 0, 0); stageB(0, 1, 0);
  stageA(1, 0, 1); stageA(1, 1, 1); stageB(1, 0, 1); stageB(1, 1, 1);

#pragma unroll
  for (int kt = 0; kt < NT; ++kt) {
    const int buf = kt & 1;
    if (kt == 0) {
      asm volatile("s_waitcnt vmcnt(8)" ::: "memory");   // T0 landed
    } else if (kt == NT - 1) {
      asm volatile("s_waitcnt vmcnt(0)" ::: "memory");   // final drain
    } else {
      asm volatile("s_waitcnt vmcnt(2)" ::: "memory");   // tile kt landed
    }
    __builtin_amdgcn_s_barrier();                        // B0
    if (kt > 0 && kt + 1 < NT) {                         // stage (kt+1).Ah1+B
      stageA(buf ^ 1, 1, kt + 1);
      stageB(buf ^ 1, 0, kt + 1);
      stageB(buf ^ 1, 1, kt + 1);
    }
    PHASEQ(buf, 0, 0)
    PHASEQ(buf, 0, 1)
    __builtin_amdgcn_s_barrier();                        // B1
    if (kt + 2 < NT) stageA(buf, 0, kt + 2);             // stage (kt+2).Ah0
    PHASEQ(buf, 1, 0)
    PHASEQ(buf, 1, 1)
  }

  // ---- epilogue: e = exp(acc+bias) -> paired u32 stores + row sums --------
  float bv[4];
#pragma unroll
  for (int nj = 0; nj < 4; ++nj) {
    const int col = bn * 256 + (nj >> 1) * 128 + wn * 32 + (nj & 1) * 16 + la;
    bv[nj] = bias[col];
  }
  const int odd = la & 1;
#pragma unroll
  for (int mi = 0; mi < 8; ++mi) {
#pragma unroll
    for (int rr = 0; rr < 4; ++rr) {
      const int rowl = (mi >> 2) * 128 + wm * 64 + (mi & 3) * 16 + lg * 4 + rr;
      const int row = bm * 256 + rowl;
      float vsum = 0.f;
#pragma unroll
      for (int nj = 0; nj < 4; ++nj) {
        const float e = expf(acc[mi][nj][rr] + bv[nj]);
        vsum += e;
        const unsigned int mine =
            (unsigned int)__builtin_bit_cast(unsigned short, (bf16_t)e);
        const unsigned int other = (unsigned int)__shfl_xor((int)mine, 1);
        if (!odd) {
          const int col = bn * 256 + (nj >> 1) * 128 + wn * 32 + (nj & 1) * 16 + la;
          *(unsigned int*)&ecache[(size_t)row * N + col] = mine | (other << 16);
        }
      }
      vsum += __shfl_xor(vsum, 1);
      vsum += __shfl_xor(vsum, 2);
      vsum += __shfl_xor(vsum, 4);
      vsum += __shfl_xor(vsum, 8);
      if (la == 0) psum[rowl][wn] = vsum;
    }
  }
  __syncthreads();
  if (tid < 256) {
    partial[(size_t)(bm * 256 + tid) * NB + bn] =
        psum[tid][0] + psum[tid][1] + psum[tid][2] + psum[tid][3];
  }
}

// ---------------------------------------------------------------------------
// 128x128 LDS GEMM (R6 pipeline, K templated) for QKV/fc/h2o.
// ---------------------------------------------------------------------------
template<int EPI, int KD>
__global__ __launch_bounds__(256) void gemm_lds(
    const bf16_t* __restrict__ A, const bf16_t* __restrict__ B,
    const float* __restrict__ bias, void* __restrict__ out, int M, int N)
{
  __shared__ bf16_t As[3][128 * 32];
  __shared__ bf16_t Bs[3][128 * 32];

  const int lane = threadIdx.x & 63;
  const int wv   = threadIdx.x >> 6;
  const int wm = wv >> 1, wn = wv & 1;
  const int bn = blockIdx.x, bm = blockIdx.y;
  const int la = lane & 15, lg = lane >> 4;
  const int tid = threadIdx.x;

  auto stage = [&](int buf, int k0) {
#pragma unroll
    for (int q = 0; q < 2; ++q) {
      const int idx = q * 256 + tid;
      const int row = idx >> 2, c = idx & 3;
      const int gch = c ^ ((row >> 1) & 3);
      GLOAD16(A + (size_t)(bm * 128 + row) * KD + k0 + gch * 8, &As[buf][idx * 8]);
      GLOAD16(B + (size_t)(bn * 128 + row) * KD + k0 + gch * 8, &Bs[buf][idx * 8]);
    }
  };
  const int rdch = (lg ^ ((la >> 1) & 3)) * 8;

  f32x4 acc[4][4] = {};
  constexpr int NT = KD >> 5;
  stage(0, 0);
  stage(1, 32);
  for (int kt = 0; kt < NT; ++kt) {
    if (kt + 1 < NT) {
      asm volatile("s_waitcnt vmcnt(4)" ::: "memory");
    } else {
      asm volatile("s_waitcnt vmcnt(0)" ::: "memory");
    }
    __builtin_amdgcn_s_barrier();
    __builtin_amdgcn_sched_barrier(0);
    if (kt + 2 < NT) stage((kt + 2) % 3, (kt + 2) * 32);
    const bf16_t* Ab = As[kt % 3];
    const bf16_t* Bb = Bs[kt % 3];
    bf16x8 a[4], b[4];
#pragma unroll
    for (int i = 0; i < 4; ++i)
      a[i] = *(const bf16x8*)(Ab + (wm * 64 + i * 16 + la) * 32 + rdch);
#pragma unroll
    for (int j = 0; j < 4; ++j)
      b[j] = *(const bf16x8*)(Bb + (wn * 64 + j * 16 + la) * 32 + rdch);
    __builtin_amdgcn_s_setprio(1);
#pragma unroll
    for (int i = 0; i < 4; ++i)
#pragma unroll
      for (int j = 0; j < 4; ++j)
        acc[i][j] = __builtin_amdgcn_mfma_f32_16x16x32_bf16(a[i], b[j], acc[i][j], 0, 0, 0);
    __builtin_amdgcn_s_setprio(0);
  }

  const int m0 = bm * 128 + wm * 64;
  const int n0 = bn * 128 + wn * 64;
  float bv4[4];
#pragma unroll
  for (int j = 0; j < 4; ++j) bv4[j] = bias[n0 + j * 16 + la];
#pragma unroll
  for (int i = 0; i < 4; ++i) {
#pragma unroll
    for (int r = 0; r < 4; ++r) {
      const int row = m0 + i * 16 + lg * 4 + r;
#pragma unroll
      for (int j = 0; j < 4; ++j) {
        const int col = n0 + j * 16 + la;
        float v = acc[i][j][r] + bv4[j];
        if constexpr (EPI == EPI_F32) {
          ((float*)out)[(size_t)row * N + col] = v;
        } else if constexpr (EPI == EPI_BF16) {
          ((bf16_t*)out)[(size_t)row * N + col] = (bf16_t)v;
        } else {
          ((bf16_t*)out)[(size_t)row * N + col] = (bf16_t)tanhf(v);
        }
      }
    }
  }
}

// ---------------------------------------------------------------------------
// Phase A mega-launch (224 blocks):
//   blocks 0..31   : GRU recurrence (unchanged structure)
//   blocks 32..223 : gi-producer -- each computes ONE 128x128 tile of
//     gi = Yemb @ WgIh^T + bIhP (192 tiles = 16 bm x 12 bn), stores via
//     AGENT-scope atomic u32 (write-through to L3; same coherence pattern
//     as the proven h-exchange), bumps giflag[bm]; then grid-strides the
//     W_out f32->bf16 cast. Consumers poll giflag[t>>1]==12 per even step.
// ---------------------------------------------------------------------------
__global__ __launch_bounds__(256) void phaseA_k(
    const bf16_t* __restrict__ Wg, const float* __restrict__ bhh,
    float* __restrict__ gi, const float* __restrict__ ct,
    unsigned int* __restrict__ hbuf, bf16_t* __restrict__ Xall,
    int* __restrict__ flags, const float* __restrict__ Wout_f32,
    bf16_t* __restrict__ WoutB, const bf16_t* __restrict__ Yemb,
    const bf16_t* __restrict__ WgIh, const float* __restrict__ bIhP)
{
  __shared__ bf16_t Wl[48 * 520];
  __shared__ float bl[48];
  __shared__ bf16_t As2[3][128 * 32];
  __shared__ bf16_t Bs2[3][128 * 32];
  const int tid = threadIdx.x, blk = blockIdx.x;

  if (blk >= NBLK_A) {                          // ---- gi producer + cast ----
    const int s = blk - NBLK_A;                 // 0..191
    const int bm = s / 12, bn = s - bm * 12;
    const int lane = tid & 63, wv = tid >> 6;
    const int wm = wv >> 1, wn = wv & 1;
    const int la = lane & 15, lg = lane >> 4;

    auto stage = [&](int buf, int k0) {
#pragma unroll
      for (int q = 0; q < 2; ++q) {
        const int idx = q * 256 + tid;
        const int row = idx >> 2, c = idx & 3;
        const int gch = c ^ ((row >> 1) & 3);
        GLOAD16(Yemb + (size_t)(bm * 128 + row) * DIN + k0 + gch * 8, &As2[buf][idx * 8]);
        GLOAD16(WgIh + (size_t)(bn * 128 + row) * DIN + k0 + gch * 8, &Bs2[buf][idx * 8]);
      }
    };
    const int rdch = (lg ^ ((la >> 1) & 3)) * 8;
    f32x4 acc[4][4] = {};
    stage(0, 0);
    stage(1, 32);
    for (int kt = 0; kt < 16; ++kt) {
      if (kt + 1 < 16) { asm volatile("s_waitcnt vmcnt(4)" ::: "memory"); }
      else             { asm volatile("s_waitcnt vmcnt(0)" ::: "memory"); }
      __builtin_amdgcn_s_barrier();
      __builtin_amdgcn_sched_barrier(0);
      if (kt + 2 < 16) stage((kt + 2) % 3, (kt + 2) * 32);
      const bf16_t* Ab = As2[kt % 3];
      const bf16_t* Bb = Bs2[kt % 3];
      bf16x8 a[4], b[4];
#pragma unroll
      for (int i = 0; i < 4; ++i)
        a[i] = *(const bf16x8*)(Ab + (wm * 64 + i * 16 + la) * 32 + rdch);
#pragma unroll
      for (int j = 0; j < 4; ++j)
        b[j] = *(const bf16x8*)(Bb + (wn * 64 + j * 16 + la) * 32 + rdch);
      __builtin_amdgcn_s_setprio(1);
#pragma unroll
      for (int i = 0; i < 4; ++i)
#pragma unroll
        for (int j = 0; j < 4; ++j)
          acc[i][j] = __builtin_amdgcn_mfma_f32_16x16x32_bf16(a[i], b[j], acc[i][j], 0, 0, 0);
      __builtin_amdgcn_s_setprio(0);
    }
    const int m0 = bm * 128 + wm * 64;
    const int n0 = bn * 128 + wn * 64;
    float bv4[4];
#pragma unroll
    for (int j = 0; j < 4; ++j) bv4[j] = bIhP[n0 + j * 16 + la];
#pragma unroll
    for (int i = 0; i < 4; ++i) {
#pragma unroll
      for (int r = 0; r < 4; ++r) {
        const int row = m0 + i * 16 + lg * 4 + r;
#pragma unroll
        for (int j = 0; j < 4; ++j) {
          const int col = n0 + j * 16 + la;
          const float v = acc[i][j][r] + bv4[j];
          __hip_atomic_store((unsigned int*)&gi[(size_t)row * G3 + col],
                             __builtin_bit_cast(unsigned int, v),
                             __ATOMIC_RELAXED, __HIP_MEMORY_SCOPE_AGENT);
        }
      }
    }
    asm volatile("s_waitcnt vmcnt(0)" ::: "memory");
    __syncthreads();
    if (tid == 0) {
      __hip_atomic_fetch_add(&flags[2048 + bm * 16], 1, __ATOMIC_RELAXED,
                             __HIP_MEMORY_SCOPE_AGENT);
    }
    // W_out cast (grid-stride over the 192 producer blocks)
    const int n4 = VOCAB * DIN / 4;
    for (int i = s * 256 + tid; i < n4; i += NBLK_GI * 256) {
      float4 v = ((const float4*)Wout_f32)[i];
      bf16x4 o = {(bf16_t)v.x, (bf16_t)v.y, (bf16_t)v.z, (bf16_t)v.w};
      *(bf16x4*)(WoutB + (size_t)i * 4) = o;
    }
    return;
  }

  // ---- GRU recurrence (blocks 0..31) ----
  for (int i = tid; i < 48 * 64; i += 256) {
    const int rw = i >> 6, ch = (i & 63) << 3;
    *(bf16x8*)(Wl + rw * 520 + ch) = *(const bf16x8*)(Wg + (size_t)(blk * 48 + rw) * 512 + ch);
  }
  if (tid < 48) bl[tid] = bhh[blk * 48 + tid];
  __syncthreads();

  const int lane = tid & 63, wv = tid >> 6;
  const int la = lane & 15, lg = lane >> 4;
  const int jcol = blk * 16 + la;
  const int rowA = wv * 16 + la;

  const float blr = bl[la], blz = bl[16 + la], bln = bl[32 + la];
  float hprev[4], ctv[4];
#pragma unroll
  for (int r = 0; r < 4; ++r) {
    hprev[r] = 0.f;
    ctv[r] = ct[(size_t)(wv * 16 + lg * 4 + r) * HID + jcol];
  }

  for (int t = 0; t < T_STEPS; ++t) {
    // gi tile readiness (12 producer blocks per 2-step row band)
    if ((t & 1) == 0) {
      while (__hip_atomic_load(&flags[2048 + (t >> 1) * 16], __ATOMIC_RELAXED,
                               __HIP_MEMORY_SCOPE_AGENT) < 12) { }
      asm volatile("" ::: "memory");
    }
    const float* girow = gi + (size_t)t * BATCH * G3 + (size_t)blk * 48;
    float gv[12];
#pragma unroll
    for (int r = 0; r < 4; ++r) {
      const float* gp = girow + (size_t)(wv * 16 + lg * 4 + r) * G3;
      gv[r * 3 + 0] = gp[la];
      gv[r * 3 + 1] = gp[16 + la];
      gv[r * 3 + 2] = gp[32 + la];
    }
    if (t > 0) {
      if (lane < 32) {
        while (__hip_atomic_load(&flags[(lane * 4 + wv) * 16], __ATOMIC_RELAXED,
                                 __HIP_MEMORY_SCOPE_AGENT) < t) { }
      }
      asm volatile("" ::: "memory");
    }
    const unsigned long long* hb =
        (const unsigned long long*)(hbuf + (size_t)(t & 1) * 16384);
    bf16x8 af[16];
#pragma unroll
    for (int q = 0; q < 16; ++q) {
      union { unsigned long long u[2]; bf16x8 v; } c;
      const size_t bidx = (size_t)(2 * q + (lg >> 1)) * 256 + rowA * 4 + (lg & 1) * 2;
      c.u[0] = __hip_atomic_load(hb + bidx,     __ATOMIC_RELAXED, __HIP_MEMORY_SCOPE_AGENT);
      c.u[1] = __hip_atomic_load(hb + bidx + 1, __ATOMIC_RELAXED, __HIP_MEMORY_SCOPE_AGENT);
      af[q] = c.v;
    }
    f32x4 acc0 = {}, acc1 = {}, acc2 = {};
#pragma unroll
    for (int q = 0; q < 16; ++q) {
      const bf16_t* wp = Wl + q * 32 + lg * 8;
      bf16x8 b0 = *(const bf16x8*)(wp + (0 * 16 + la) * 520);
      bf16x8 b1 = *(const bf16x8*)(wp + (1 * 16 + la) * 520);
      bf16x8 b2 = *(const bf16x8*)(wp + (2 * 16 + la) * 520);
      acc0 = __builtin_amdgcn_mfma_f32_16x16x32_bf16(af[q], b0, acc0, 0, 0, 0);
      acc1 = __builtin_amdgcn_mfma_f32_16x16x32_bf16(af[q], b1, acc1, 0, 0, 0);
      acc2 = __builtin_amdgcn_mfma_f32_16x16x32_bf16(af[q], b2, acc2, 0, 0, 0);
    }
    float h1v[4];
#pragma unroll
    for (int r = 0; r < 4; ++r) {
      const float ghr = acc0[r] + blr;
      const float ghz = acc1[r] + blz;
      const float ghn = acc2[r] + bln;
      const float rr = 1.f / (1.f + expf(-(gv[r * 3 + 0] + ghr)));
      const float zz = 1.f / (1.f + expf(-(gv[r * 3 + 1] + ghz)));
      const float nn = tanhf(gv[r * 3 + 2] + rr * ghn);
      h1v[r] = (1.f - zz) * nn + zz * hprev[r];
      hprev[r] = h1v[r];
    }
    unsigned int* hn = hbuf + (size_t)((t + 1) & 1) * 16384 + blk * 512;
#pragma unroll
    for (int r = 0; r < 4; ++r) {
      const int row = wv * 16 + lg * 4 + r;
      const unsigned int mine =
          (unsigned int)__builtin_bit_cast(unsigned short, (bf16_t)h1v[r]);
      const unsigned int other = (unsigned int)__shfl_xor((int)mine, 1);
      if ((la & 1) == 0) {
        __hip_atomic_store(hn + row * 8 + (la >> 1), mine | (other << 16),
                           __ATOMIC_RELAXED, __HIP_MEMORY_SCOPE_AGENT);
      }
    }
    asm volatile("s_waitcnt vmcnt(0)" ::: "memory");
    if (lane == 0) {
      __hip_atomic_store(&flags[(blk * 4 + wv) * 16], t + 1, __ATOMIC_RELAXED,
                         __HIP_MEMORY_SCOPE_AGENT);
    }
#pragma unroll
    for (int r = 0; r < 4; ++r) {
      const int row = wv * 16 + lg * 4 + r;
      Xall[((size_t)t * BATCH + row) * HID + jcol] = (bf16_t)(h1v[r] * ctv[r]);
    }
  }
}

// ---------------------------------------------------------------------------
__global__ __launch_bounds__(256) void attn_k(const bf16_t* __restrict__ QKV,
                                              bf16_t* __restrict__ attO)
{
  __shared__ float sq[4][512], sk[4][512], sv[4][512], sw[4][64];
  const int tid = threadIdx.x;
  const int wv = tid >> 6, lane = tid & 63;
  const int row = blockIdx.x * 4 + wv;
  const bf16_t* base = QKV + (size_t)row * G3;
  bf16x8 vq = *(const bf16x8*)(base + lane * 8);
  bf16x8 vk = *(const bf16x8*)(base + 512 + lane * 8);
  bf16x8 vv = *(const bf16x8*)(base + 1024 + lane * 8);
#pragma unroll
  for (int e = 0; e < 8; ++e) {
    sq[wv][lane * 8 + e] = (float)vq[e];
    sk[wv][lane * 8 + e] = (float)vk[e];
    sv[wv][lane * 8 + e] = (float)vv[e];
  }
  __syncthreads();
  const int h = lane >> 3, g = lane & 7;
  float s = 0.f;
#pragma unroll 16
  for (int d = 0; d < 64; ++d) s += sq[wv][h * 64 + d] * sk[wv][g * 64 + d];
  s *= (1.f / 64.f);
  float m = s;
  m = fmaxf(m, __shfl_xor(m, 1));
  m = fmaxf(m, __shfl_xor(m, 2));
  m = fmaxf(m, __shfl_xor(m, 4));
  const float e = expf(s - m);
  float sum = e;
  sum += __shfl_xor(sum, 1);
  sum += __shfl_xor(sum, 2);
  sum += __shfl_xor(sum, 4);
  sw[wv][lane] = e / sum;
  __syncthreads();
#pragma unroll
  for (int rep = 0; rep < 8; ++rep) {
    const int idx = rep * 64 + lane;
    const int hh = idx >> 6, d = idx & 63;
    float o = 0.f;
#pragma unroll
    for (int gg = 0; gg < 8; ++gg) o += sw[wv][hh * 8 + gg] * sv[wv][gg * 64 + d];
    attO[(size_t)row * HID + idx] = (bf16_t)o;
  }
}

// --------------------------- small prep kernels ----------------------------
__global__ __launch_bounds__(256) void cast5_k(
    const float* __restrict__ s0, const float* __restrict__ s1,
    const float* __restrict__ s2, const float* __restrict__ s3,
    const float* __restrict__ s4, bf16_t* __restrict__ Wqkv,
    bf16_t* __restrict__ WfcB, bf16_t* __restrict__ Wh2oB)
{
  const int seg = blockIdx.x >> 8;
  const int i = (blockIdx.x & 255) * 256 + threadIdx.x;
  const float* src = seg == 0 ? s0 : seg == 1 ? s1 : seg == 2 ? s2
                   : seg == 3 ? s3 : s4;
  bf16_t* dst = seg <= 2 ? Wqkv + (size_t)seg * HID * DIN
              : seg == 3 ? WfcB : Wh2oB;
  float4 v = ((const float4*)src)[i];
  bf16x4 o = {(bf16_t)v.x, (bf16_t)v.y, (bf16_t)v.z, (bf16_t)v.w};
  *(bf16x4*)(dst + (size_t)i * 4) = o;
}

__global__ __launch_bounds__(256) void perm_cast_k(const float* __restrict__ src,
                                                   bf16_t* __restrict__ dst)
{
  const int i = blockIdx.x * 256 + threadIdx.x;
  const int pg = i >> 7, kq = (i & 127) << 2;
  const int g = pg / 48, rem = pg - g * 48, sec = rem >> 4, jj = rem & 15;
  const int srow = sec * 512 + g * 16 + jj;
  float4 v = *(const float4*)(src + (size_t)srow * DIN + kq);
  bf16x4 o = {(bf16_t)v.x, (bf16_t)v.y, (bf16_t)v.z, (bf16_t)v.w};
  *(bf16x4*)(dst + (size_t)pg * DIN + kq) = o;
}

__global__ void perm_bias_k(const float* __restrict__ bih, const float* __restrict__ bhh,
                            float* __restrict__ bihp, float* __restrict__ bhhp)
{
  const int pg = blockIdx.x * 256 + threadIdx.x;
  if (pg >= G3) return;
  const int g = pg / 48, rem = pg - g * 48, sec = rem >> 4, jj = rem & 15;
  const int srow = sec * 512 + g * 16 + jj;
  bihp[pg] = bih[srow];
  bhhp[pg] = bhh[srow];
}

__global__ void bcat_k(const float* __restrict__ a, const float* __restrict__ b,
                       const float* __restrict__ c, float* __restrict__ d)
{
  const int i = blockIdx.x * 256 + threadIdx.x;
  if (i >= G3) return;
  d[i] = i < 512 ? a[i] : (i < 1024 ? b[i - 512] : c[i - 1024]);
}

__global__ __launch_bounds__(256) void yemb_k(const int* __restrict__ y,
                                              const float* __restrict__ embW,
                                              bf16_t* __restrict__ out)
{
  const int idx = blockIdx.x * 256 + threadIdx.x;
  const int rb = idx >> 6, c = (idx & 63) << 3;
  const int tok = y[rb];
  const float4* s = (const float4*)(embW + (size_t)tok * DIN + c);
  float4 v0 = s[0], v1 = s[1];
  bf16x8 o = {(bf16_t)v0.x, (bf16_t)v0.y, (bf16_t)v0.z, (bf16_t)v0.w,
              (bf16_t)v1.x, (bf16_t)v1.y, (bf16_t)v1.z, (bf16_t)v1.w};
  *(bf16x8*)(out + (size_t)rb * DIN + c) = o;
}

__global__ __launch_bounds__(256) void ct_k(const float* __restrict__ ctx,
                                            const float* __restrict__ Watt,
                                            const float* __restrict__ batt,
                                            float* __restrict__ ct)
{
  const int idx = blockIdx.x * 256 + threadIdx.x;
  const int b = idx >> 9, j = idx & 511;
  const float4* c4 = (const float4*)(ctx + (size_t)b * FFEAT);
  const float4* w4 = (const float4*)(Watt + (size_t)j * FFEAT);
  float s = batt[j];
  for (int q = 0; q < FFEAT / 4; ++q) {
    float4 cc = c4[q], ww = w4[q];
    s += cc.x * ww.x + cc.y * ww.y + cc.z * ww.z + cc.w * ww.w;
  }
  ct[idx] = tanhf(s);
}

__global__ __launch_bounds__(256) void reduce_rows(const float* __restrict__ partial,
                                                   float* __restrict__ rowsum, int NB)
{
  const int wv = threadIdx.x >> 6, lane = threadIdx.x & 63;
  const int row = blockIdx.x * 4 + wv;
  float s = 0.f;
  for (int c = lane; c < NB; c += 64) s += partial[(size_t)row * NB + c];
  for (int m = 1; m < 64; m <<= 1) s += __shfl_xor(s, m);
  if (lane == 0) rowsum[row] = s;
}

__global__ __launch_bounds__(256) void normalize_k(const bf16_t* __restrict__ e,
                                                   const float* __restrict__ rowsum,
                                                   float* __restrict__ out)
{
  const int row = blockIdx.y;
  const int c8 = blockIdx.x * 256 + threadIdx.x;
  if (c8 >= VOCAB / 8) return;
  const float inv = 1.0f / rowsum[row];
  const size_t base = (size_t)row * VOCAB + (size_t)c8 * 8;
  bf16x8 v = *(const bf16x8*)(e + base);
  float4 o0 = {(float)v[0] * inv, (float)v[1] * inv, (float)v[2] * inv, (float)v[3] * inv};
  float4 o1 = {(float)v[4] * inv, (float)v[5] * inv, (float)v[6] * inv, (float)v[7] * inv};
  *(float4*)(out + base) = o0;
  *(float4*)(out + base + 4) = o1;
}

// ---------------------------------------------------------------------------
extern "C" void kernel_launch(void* const* d_in, const int* in_sizes, int n_in,
                              void* d_out, int out_size, void* d_ws, size_t ws_size,
                              hipStream_t stream)
{
  const int*   y     = (const int*)  d_in[0];
  const float* ctx   = (const float*)d_in[1];
  const float* embW  = (const float*)d_in[2];
  const float* W_ih  = (const float*)d_in[3];
  const float* b_ih  = (const float*)d_in[4];
  const float* W_hh  = (const float*)d_in[5];
  const float* b_hh  = (const float*)d_in[6];
  const float* W_att = (const float*)d_in[7];
  const float* b_att = (const float*)d_in[8];
  const float* Wq    = (const float*)d_in[9];
  const float* bq    = (const float*)d_in[10];
  const float* Wk    = (const float*)d_in[11];
  const float* bk    = (const float*)d_in[12];
  const float* Wv    = (const float*)d_in[13];
  const float* bv    = (const float*)d_in[14];
  const float* Wfc   = (const float*)d_in[15];
  const float* bfc   = (const float*)d_in[16];
  const float* Wh2o  = (const float*)d_in[17];
  const float* bh2o  = (const float*)d_in[18];
  const float* W_out = (const float*)d_in[19];
  const float* b_out = (const float*)d_in[20];

  char* p = (char*)d_ws;
  auto alloc = [&](size_t bytes) {
    char* r = p;
    p += (bytes + 255) & ~(size_t)255;
    return r;
  };
  bf16_t* WoutB   = (bf16_t*)alloc((size_t)VOCAB * DIN * 2);
  bf16_t* WgIh    = (bf16_t*)alloc((size_t)G3 * DIN * 2);
  bf16_t* WgHh    = (bf16_t*)alloc((size_t)G3 * DIN * 2);
  bf16_t* Wqkv    = (bf16_t*)alloc((size_t)G3 * DIN * 2);
  bf16_t* WfcB    = (bf16_t*)alloc((size_t)HID * HID * 2);
  bf16_t* Wh2oB   = (bf16_t*)alloc((size_t)HID * HID * 2);
  float*  bIhP    = (float*)alloc(G3 * 4);
  float*  bHhP    = (float*)alloc(G3 * 4);
  float*  bQkv    = (float*)alloc(G3 * 4);
  bf16_t* Yemb    = (bf16_t*)alloc((size_t)ROWS * DIN * 2);
  float*  giP     = (float*)alloc((size_t)ROWS * G3 * 4);
  float*  ctB     = (float*)alloc((size_t)BATCH * HID * 4);
  unsigned int* hbuf = (unsigned int*)alloc((size_t)2 * 16384 * 4);
  bf16_t* Xall    = (bf16_t*)alloc((size_t)ROWS * DIN * 2);
  bf16_t* QKV     = (bf16_t*)alloc((size_t)ROWS * G3 * 2);
  bf16_t* attO    = (bf16_t*)alloc((size_t)ROWS * HID * 2);
  bf16_t* h2B     = (bf16_t*)alloc((size_t)ROWS * HID * 2);
  bf16_t* logit   = (bf16_t*)alloc((size_t)ROWS * DIN * 2);
  float*  partial = (float*)alloc((size_t)ROWS * 125 * 4);
  float*  rowsum  = (float*)alloc((size_t)ROWS * 4);
  int*    flags   = (int*)alloc(16384);        // h-flags [0,8K) + gi-flags [8K,9K)
  bf16_t* eCache  = (bf16_t*)alloc((size_t)ROWS * VOCAB * 2);   // 131 MB

  hipMemsetAsync(hbuf, 0, (size_t)2 * 16384 * 4, stream);
  hipMemsetAsync(flags, 0, 16384, stream);

  // weight prep (gi-GEMM + W_out cast fused into phaseA launch below)
  cast5_k<<<1280, 256, 0, stream>>>(Wq, Wk, Wv, Wfc, Wh2o, Wqkv, WfcB, Wh2oB);
  perm_cast_k<<<768, 256, 0, stream>>>(W_ih, WgIh);
  perm_cast_k<<<768, 256, 0, stream>>>(W_hh, WgHh);
  perm_bias_k<<<6, 256, 0, stream>>>(b_ih, b_hh, bIhP, bHhP);
  bcat_k<<<6, 256, 0, stream>>>(bq, bk, bv, bQkv);
  yemb_k<<<512, 256, 0, stream>>>(y, embW, Yemb);
  ct_k<<<128, 256, 0, stream>>>(ctx, W_att, b_att, ctB);

  // GRU recurrence (0-31) + gi producers (32-223, then W_out cast)
  phaseA_k<<<NBLK_A + NBLK_GI, 256, 0, stream>>>(
      WgHh, bHhP, giP, ctB, hbuf, Xall, flags, W_out, WoutB, Yemb, WgIh, bIhP);

  // QKV = X @ [Wq;Wk;Wv]^T + b
  gemm_lds<EPI_BF16, DIN><<<dim3(12, 16), 256, 0, stream>>>(
      Xall, Wqkv, bQkv, QKV, ROWS, G3);

  attn_k<<<512, 256, 0, stream>>>(QKV, attO);

  gemm_lds<EPI_BF16, HID><<<dim3(4, 16), 256, 0, stream>>>(
      attO, WfcB, bfc, h2B, ROWS, HID);

  gemm_lds<EPI_TANH, HID><<<dim3(4, 16), 256, 0, stream>>>(
      h2B, Wh2oB, bh2o, logit, ROWS, DIN);

  // vocab: single GEMM -> bf16 exp cache + partial sums (NB = 125)
  gemm_v<DIN><<<1000, 512, 0, stream>>>(
      logit, WoutB, b_out, eCache, partial, ROWS, VOCAB, 125);
  reduce_rows<<<512, 256, 0, stream>>>(partial, rowsum, 125);
  normalize_k<<<dim3(16, ROWS), 256, 0, stream>>>(eCache, rowsum, (float*)d_out);
}

// Round 13
// 439.466 us; speedup vs baseline: 1.1443x; 1.0001x over previous
//
#include <hip/hip_runtime.h>
#include <hip/hip_bf16.h>
#include <math.h>

typedef __bf16 bf16_t;
typedef __bf16 bf16x8 __attribute__((ext_vector_type(8)));
typedef __bf16 bf16x4 __attribute__((ext_vector_type(4)));
typedef float  f32x4  __attribute__((ext_vector_type(4)));

#define T_STEPS 32
#define BATCH   64
#define DIN     512
#define HID     512
#define VOCAB   32000
#define FFEAT   768
#define ROWS    2048   /* T*B */
#define G3      1536   /* 3*H */
#define NBLK_A  32
#define NBLK_GI 192    /* gi-producer blocks in phaseA launch */

#define EPI_F32  0
#define EPI_BF16 1
#define EPI_TANH 2

#define GLOAD16(gp, lp) __builtin_amdgcn_global_load_lds( \
    (const __attribute__((address_space(1))) void*)(gp),  \
    (__attribute__((address_space(3))) void*)(lp), 16, 0, 0)

// ===========================================================================
// gemm_v: 256x256 VOCAB GEMM, barrier-minimized (R11).
// Same fragment mapping/swizzle as R10 (proven: 0 bank conflicts) but the
// schedule is 8 K-tiles of BK=64, each = [gate; barrier B0; stage; ph0; ph1;
// barrier B1; stage; ph2; ph3] -- 2 barriers/tile (17 total vs 65). Within a
// tile the 4 phases are straight-line (32 ds_read + 64 MFMA ILP window).
// Stage ledger (target tile X -> buf[X&1]):
//   X.Ah0     @ B1(X-2)   (buf.Ah0 dead after X-2's ph0-1)
//   X.Ah1,X.B @ B0(X-1)   (buf^1 regions dead at X-1 entry)
// Gate at B0(kt): loads issued before = ...,B0(kt-1):[kt.Ah1,kt.B x6],
// B1(kt-1):[kt+1.Ah0 x2] -> vmcnt(2) ensures tile kt landed (kt=0: vmcnt(8)
// after 16-load prologue; kt=NT-1: vmcnt(0), nothing staged after).
// ===========================================================================
#define PHASEQ(BUF, MH, KS)                                                   \
  {                                                                           \
    bf16x8 af_[4], bf_[4];                                                    \
    _Pragma("unroll")                                                         \
    for (int m2 = 0; m2 < 4; ++m2) {                                          \
      const int row = wm * 64 + m2 * 16 + la;                                 \
      const int sl = ((KS) * 4 + lg) ^ (row & 7);                             \
      af_[m2] =                                                               \
          *(const bf16x8*)&lds[((BUF)*4 + (MH)) * 8192 + row * 64 + sl * 8];  \
    }                                                                         \
    _Pragma("unroll")                                                         \
    for (int nj = 0; nj < 4; ++nj) {                                          \
      const int row = wn * 32 + (nj & 1) * 16 + la;                           \
      const int sl = ((KS) * 4 + lg) ^ (row & 7);                             \
      bf_[nj] =                                                               \
          *(const bf16x8*)&lds[((BUF)*4 + 2 + (nj >> 1)) * 8192 + row * 64 + sl * 8];\
    }                                                                         \
    __builtin_amdgcn_s_setprio(1);                                            \
    _Pragma("unroll")                                                         \
    for (int m2 = 0; m2 < 4; ++m2)                                            \
      _Pragma("unroll")                                                       \
      for (int nj = 0; nj < 4; ++nj)                                          \
        acc[(MH)*4 + m2][nj] =                                                \
            __builtin_amdgcn_mfma_f32_16x16x32_bf16(                          \
                af_[m2], bf_[nj], acc[(MH)*4 + m2][nj], 0, 0, 0);             \
    __builtin_amdgcn_s_setprio(0);                                            \
  }

template<int KD>
__global__ __launch_bounds__(512, 2) void gemm_v(
    const bf16_t* __restrict__ A, const bf16_t* __restrict__ B,
    const float* __restrict__ bias, bf16_t* __restrict__ ecache,
    float* __restrict__ partial, int M, int N, int NB)
{
  __shared__ bf16_t lds[2 * 4 * 8192];   // 128 KB
  __shared__ float psum[256][4];
  const int tid = threadIdx.x;
  const int lane = tid & 63, wv = tid >> 6;
  const int wm = wv >> 2, wn = wv & 3;
  const int la = lane & 15, lg = lane >> 4;

  // bn-major XCD-chunk swizzle (nwg = NB * M/256, multiple of 8)
  const int lin = blockIdx.x;
  const int mt = M >> 8;                       // 8
  const int cpx = (NB * mt) >> 3;
  const int wg = (lin & 7) * cpx + (lin >> 3);
  const int bn = wg / mt, bm = wg - bn * mt;

  auto stageA = [&](int buf, int h, int kt) {
    const size_t base = (size_t)(bm * 256 + h * 128) * KD + (size_t)kt * 64;
#pragma unroll
    for (int q = 0; q < 2; ++q) {
      const int L = q * 512 + tid;
      const int row = L >> 3, sl = L & 7;
      const int c = sl ^ (row & 7);
      GLOAD16(A + base + (size_t)row * KD + c * 8,
              &lds[(buf * 4 + h) * 8192 + L * 8]);
    }
  };
  auto stageB = [&](int buf, int h, int kt) {
    const size_t base = (size_t)(bn * 256 + h * 128) * KD + (size_t)kt * 64;
#pragma unroll
    for (int q = 0; q < 2; ++q) {
      const int L = q * 512 + tid;
      const int row = L >> 3, sl = L & 7;
      const int c = sl ^ (row & 7);
      GLOAD16(B + base + (size_t)row * KD + c * 8,
              &lds[(buf * 4 + 2 + h) * 8192 + L * 8]);
    }
  };

  f32x4 acc[8][4] = {};
  constexpr int NT = KD >> 6;                  // 8 for K=512

  // prologue: T0 + T1 fully staged (16 loads/thread)
  stageA(0, 0, 0); stageA(0, 1, 0); stageB(0, 0, 0); stageB(0, 1, 0);
  stageA(1, 0, 1); stageA(1, 1, 1); stageB(1, 0, 1); stageB(1, 1, 1);

#pragma unroll
  for (int kt = 0; kt < NT; ++kt) {
    const int buf = kt & 1;
    if (kt == 0) {
      asm volatile("s_waitcnt vmcnt(8)" ::: "memory");   // T0 landed
    } else if (kt == NT - 1) {
      asm volatile("s_waitcnt vmcnt(0)" ::: "memory");   // final drain
    } else {
      asm volatile("s_waitcnt vmcnt(2)" ::: "memory");   // tile kt landed
    }
    __builtin_amdgcn_s_barrier();                        // B0
    if (kt > 0 && kt + 1 < NT) {                         // stage (kt+1).Ah1+B
      stageA(buf ^ 1, 1, kt + 1);
      stageB(buf ^ 1, 0, kt + 1);
      stageB(buf ^ 1, 1, kt + 1);
    }
    PHASEQ(buf, 0, 0)
    PHASEQ(buf, 0, 1)
    __builtin_amdgcn_s_barrier();                        // B1
    if (kt + 2 < NT) stageA(buf, 0, kt + 2);             // stage (kt+2).Ah0
    PHASEQ(buf, 1, 0)
    PHASEQ(buf, 1, 1)
  }

  // ---- epilogue: e = exp(acc+bias) -> paired u32 stores + row sums --------
  float bv[4];
#pragma unroll
  for (int nj = 0; nj < 4; ++nj) {
    const int col = bn * 256 + (nj >> 1) * 128 + wn * 32 + (nj & 1) * 16 + la;
    bv[nj] = bias[col];
  }
  const int odd = la & 1;
#pragma unroll
  for (int mi = 0; mi < 8; ++mi) {
#pragma unroll
    for (int rr = 0; rr < 4; ++rr) {
      const int rowl = (mi >> 2) * 128 + wm * 64 + (mi & 3) * 16 + lg * 4 + rr;
      const int row = bm * 256 + rowl;
      float vsum = 0.f;
#pragma unroll
      for (int nj = 0; nj < 4; ++nj) {
        const float e = expf(acc[mi][nj][rr] + bv[nj]);
        vsum += e;
        const unsigned int mine =
            (unsigned int)__builtin_bit_cast(unsigned short, (bf16_t)e);
        const unsigned int other = (unsigned int)__shfl_xor((int)mine, 1);
        if (!odd) {
          const int col = bn * 256 + (nj >> 1) * 128 + wn * 32 + (nj & 1) * 16 + la;
          *(unsigned int*)&ecache[(size_t)row * N + col] = mine | (other << 16);
        }
      }
      vsum += __shfl_xor(vsum, 1);
      vsum += __shfl_xor(vsum, 2);
      vsum += __shfl_xor(vsum, 4);
      vsum += __shfl_xor(vsum, 8);
      if (la == 0) psum[rowl][wn] = vsum;
    }
  }
  __syncthreads();
  if (tid < 256) {
    partial[(size_t)(bm * 256 + tid) * NB + bn] =
        psum[tid][0] + psum[tid][1] + psum[tid][2] + psum[tid][3];
  }
}

// ---------------------------------------------------------------------------
// 128x128 LDS GEMM (R6 pipeline, K templated) for QKV/fc/h2o.
// ---------------------------------------------------------------------------
template<int EPI, int KD>
__global__ __launch_bounds__(256) void gemm_lds(
    const bf16_t* __restrict__ A, const bf16_t* __restrict__ B,
    const float* __restrict__ bias, void* __restrict__ out, int M, int N)
{
  __shared__ bf16_t As[3][128 * 32];
  __shared__ bf16_t Bs[3][128 * 32];

  const int lane = threadIdx.x & 63;
  const int wv   = threadIdx.x >> 6;
  const int wm = wv >> 1, wn = wv & 1;
  const int bn = blockIdx.x, bm = blockIdx.y;
  const int la = lane & 15, lg = lane >> 4;
  const int tid = threadIdx.x;

  auto stage = [&](int buf, int k0) {
#pragma unroll
    for (int q = 0; q < 2; ++q) {
      const int idx = q * 256 + tid;
      const int row = idx >> 2, c = idx & 3;
      const int gch = c ^ ((row >> 1) & 3);
      GLOAD16(A + (size_t)(bm * 128 + row) * KD + k0 + gch * 8, &As[buf][idx * 8]);
      GLOAD16(B + (size_t)(bn * 128 + row) * KD + k0 + gch * 8, &Bs[buf][idx * 8]);
    }
  };
  const int rdch = (lg ^ ((la >> 1) & 3)) * 8;

  f32x4 acc[4][4] = {};
  constexpr int NT = KD >> 5;
  stage(0, 0);
  stage(1, 32);
  for (int kt = 0; kt < NT; ++kt) {
    if (kt + 1 < NT) {
      asm volatile("s_waitcnt vmcnt(4)" ::: "memory");
    } else {
      asm volatile("s_waitcnt vmcnt(0)" ::: "memory");
    }
    __builtin_amdgcn_s_barrier();
    __builtin_amdgcn_sched_barrier(0);
    if (kt + 2 < NT) stage((kt + 2) % 3, (kt + 2) * 32);
    const bf16_t* Ab = As[kt % 3];
    const bf16_t* Bb = Bs[kt % 3];
    bf16x8 a[4], b[4];
#pragma unroll
    for (int i = 0; i < 4; ++i)
      a[i] = *(const bf16x8*)(Ab + (wm * 64 + i * 16 + la) * 32 + rdch);
#pragma unroll
    for (int j = 0; j < 4; ++j)
      b[j] = *(const bf16x8*)(Bb + (wn * 64 + j * 16 + la) * 32 + rdch);
    __builtin_amdgcn_s_setprio(1);
#pragma unroll
    for (int i = 0; i < 4; ++i)
#pragma unroll
      for (int j = 0; j < 4; ++j)
        acc[i][j] = __builtin_amdgcn_mfma_f32_16x16x32_bf16(a[i], b[j], acc[i][j], 0, 0, 0);
    __builtin_amdgcn_s_setprio(0);
  }

  const int m0 = bm * 128 + wm * 64;
  const int n0 = bn * 128 + wn * 64;
  float bv4[4];
#pragma unroll
  for (int j = 0; j < 4; ++j) bv4[j] = bias[n0 + j * 16 + la];
#pragma unroll
  for (int i = 0; i < 4; ++i) {
#pragma unroll
    for (int r = 0; r < 4; ++r) {
      const int row = m0 + i * 16 + lg * 4 + r;
#pragma unroll
      for (int j = 0; j < 4; ++j) {
        const int col = n0 + j * 16 + la;
        float v = acc[i][j][r] + bv4[j];
        if constexpr (EPI == EPI_F32) {
          ((float*)out)[(size_t)row * N + col] = v;
        } else if constexpr (EPI == EPI_BF16) {
          ((bf16_t*)out)[(size_t)row * N + col] = (bf16_t)v;
        } else {
          ((bf16_t*)out)[(size_t)row * N + col] = (bf16_t)tanhf(v);
        }
      }
    }
  }
}

// ---------------------------------------------------------------------------
// Phase A mega-launch (224 blocks):
//   blocks 0..31   : GRU recurrence (unchanged structure)
//   blocks 32..223 : gi-producer -- each computes ONE 128x128 tile of
//     gi = Yemb @ WgIh^T + bIhP (192 tiles = 16 bm x 12 bn), stores via
//     AGENT-scope atomic u32 (write-through to L3; same coherence pattern
//     as the proven h-exchange), bumps giflag[bm]; then grid-strides the
//     W_out f32->bf16 cast. Consumers poll giflag[t>>1]==12 per even step.
// ---------------------------------------------------------------------------
__global__ __launch_bounds__(256) void phaseA_k(
    const bf16_t* __restrict__ Wg, const float* __restrict__ bhh,
    float* __restrict__ gi, const float* __restrict__ ct,
    unsigned int* __restrict__ hbuf, bf16_t* __restrict__ Xall,
    int* __restrict__ flags, const float* __restrict__ Wout_f32,
    bf16_t* __restrict__ WoutB, const bf16_t* __restrict__ Yemb,
    const bf16_t* __restrict__ WgIh, const float* __restrict__ bIhP)
{
  __shared__ bf16_t Wl[48 * 520];
  __shared__ float bl[48];
  __shared__ bf16_t As2[3][128 * 32];
  __shared__ bf16_t Bs2[3][128 * 32];
  const int tid = threadIdx.x, blk = blockIdx.x;

  if (blk >= NBLK_A) {                          // ---- gi producer + cast ----
    const int s = blk - NBLK_A;                 // 0..191
    const int bm = s / 12, bn = s - bm * 12;
    const int lane = tid & 63, wv = tid >> 6;
    const int wm = wv >> 1, wn = wv & 1;
    const int la = lane & 15, lg = lane >> 4;

    auto stage = [&](int buf, int k0) {
#pragma unroll
      for (int q = 0; q < 2; ++q) {
        const int idx = q * 256 + tid;
        const int row = idx >> 2, c = idx & 3;
        const int gch = c ^ ((row >> 1) & 3);
        GLOAD16(Yemb + (size_t)(bm * 128 + row) * DIN + k0 + gch * 8, &As2[buf][idx * 8]);
        GLOAD16(WgIh + (size_t)(bn * 128 + row) * DIN + k0 + gch * 8, &Bs2[buf][idx * 8]);
      }
    };
    const int rdch = (lg ^ ((la >> 1) & 3)) * 8;
    f32x4 acc[4][4] = {};
    stage(0, 0);
    stage(1, 32);
    for (int kt = 0; kt < 16; ++kt) {
      if (kt + 1 < 16) { asm volatile("s_waitcnt vmcnt(4)" ::: "memory"); }
      else             { asm volatile("s_waitcnt vmcnt(0)" ::: "memory"); }
      __builtin_amdgcn_s_barrier();
      __builtin_amdgcn_sched_barrier(0);
      if (kt + 2 < 16) stage((kt + 2) % 3, (kt + 2) * 32);
      const bf16_t* Ab = As2[kt % 3];
      const bf16_t* Bb = Bs2[kt % 3];
      bf16x8 a[4], b[4];
#pragma unroll
      for (int i = 0; i < 4; ++i)
        a[i] = *(const bf16x8*)(Ab + (wm * 64 + i * 16 + la) * 32 + rdch);
#pragma unroll
      for (int j = 0; j < 4; ++j)
        b[j] = *(const bf16x8*)(Bb + (wn * 64 + j * 16 + la) * 32 + rdch);
      __builtin_amdgcn_s_setprio(1);
#pragma unroll
      for (int i = 0; i < 4; ++i)
#pragma unroll
        for (int j = 0; j < 4; ++j)
          acc[i][j] = __builtin_amdgcn_mfma_f32_16x16x32_bf16(a[i], b[j], acc[i][j], 0, 0, 0);
      __builtin_amdgcn_s_setprio(0);
    }
    const int m0 = bm * 128 + wm * 64;
    const int n0 = bn * 128 + wn * 64;
    float bv4[4];
#pragma unroll
    for (int j = 0; j < 4; ++j) bv4[j] = bIhP[n0 + j * 16 + la];
#pragma unroll
    for (int i = 0; i < 4; ++i) {
#pragma unroll
      for (int r = 0; r < 4; ++r) {
        const int row = m0 + i * 16 + lg * 4 + r;
#pragma unroll
        for (int j = 0; j < 4; ++j) {
          const int col = n0 + j * 16 + la;
          const float v = acc[i][j][r] + bv4[j];
          __hip_atomic_store((unsigned int*)&gi[(size_t)row * G3 + col],
                             __builtin_bit_cast(unsigned int, v),
                             __ATOMIC_RELAXED, __HIP_MEMORY_SCOPE_AGENT);
        }
      }
    }
    asm volatile("s_waitcnt vmcnt(0)" ::: "memory");
    __syncthreads();
    if (tid == 0) {
      __hip_atomic_fetch_add(&flags[2048 + bm * 16], 1, __ATOMIC_RELAXED,
                             __HIP_MEMORY_SCOPE_AGENT);
    }
    // W_out cast (grid-stride over the 192 producer blocks)
    const int n4 = VOCAB * DIN / 4;
    for (int i = s * 256 + tid; i < n4; i += NBLK_GI * 256) {
      float4 v = ((const float4*)Wout_f32)[i];
      bf16x4 o = {(bf16_t)v.x, (bf16_t)v.y, (bf16_t)v.z, (bf16_t)v.w};
      *(bf16x4*)(WoutB + (size_t)i * 4) = o;
    }
    return;
  }

  // ---- GRU recurrence (blocks 0..31) ----
  for (int i = tid; i < 48 * 64; i += 256) {
    const int rw = i >> 6, ch = (i & 63) << 3;
    *(bf16x8*)(Wl + rw * 520 + ch) = *(const bf16x8*)(Wg + (size_t)(blk * 48 + rw) * 512 + ch);
  }
  if (tid < 48) bl[tid] = bhh[blk * 48 + tid];
  __syncthreads();

  const int lane = tid & 63, wv = tid >> 6;
  const int la = lane & 15, lg = lane >> 4;
  const int jcol = blk * 16 + la;
  const int rowA = wv * 16 + la;

  const float blr = bl[la], blz = bl[16 + la], bln = bl[32 + la];
  float hprev[4], ctv[4];
#pragma unroll
  for (int r = 0; r < 4; ++r) {
    hprev[r] = 0.f;
    ctv[r] = ct[(size_t)(wv * 16 + lg * 4 + r) * HID + jcol];
  }

  for (int t = 0; t < T_STEPS; ++t) {
    // gi tile readiness (12 producer blocks per 2-step row band)
    if ((t & 1) == 0) {
      while (__hip_atomic_load(&flags[2048 + (t >> 1) * 16], __ATOMIC_RELAXED,
                               __HIP_MEMORY_SCOPE_AGENT) < 12) { }
      asm volatile("" ::: "memory");
    }
    const float* girow = gi + (size_t)t * BATCH * G3 + (size_t)blk * 48;
    float gv[12];
#pragma unroll
    for (int r = 0; r < 4; ++r) {
      const float* gp = girow + (size_t)(wv * 16 + lg * 4 + r) * G3;
      gv[r * 3 + 0] = gp[la];
      gv[r * 3 + 1] = gp[16 + la];
      gv[r * 3 + 2] = gp[32 + la];
    }
    if (t > 0) {
      if (lane < 32) {
        while (__hip_atomic_load(&flags[(lane * 4 + wv) * 16], __ATOMIC_RELAXED,
                                 __HIP_MEMORY_SCOPE_AGENT) < t) { }
      }
      asm volatile("" ::: "memory");
    }
    const unsigned long long* hb =
        (const unsigned long long*)(hbuf + (size_t)(t & 1) * 16384);
    bf16x8 af[16];
#pragma unroll
    for (int q = 0; q < 16; ++q) {
      union { unsigned long long u[2]; bf16x8 v; } c;
      const size_t bidx = (size_t)(2 * q + (lg >> 1)) * 256 + rowA * 4 + (lg & 1) * 2;
      c.u[0] = __hip_atomic_load(hb + bidx,     __ATOMIC_RELAXED, __HIP_MEMORY_SCOPE_AGENT);
      c.u[1] = __hip_atomic_load(hb + bidx + 1, __ATOMIC_RELAXED, __HIP_MEMORY_SCOPE_AGENT);
      af[q] = c.v;
    }
    f32x4 acc0 = {}, acc1 = {}, acc2 = {};
#pragma unroll
    for (int q = 0; q < 16; ++q) {
      const bf16_t* wp = Wl + q * 32 + lg * 8;
      bf16x8 b0 = *(const bf16x8*)(wp + (0 * 16 + la) * 520);
      bf16x8 b1 = *(const bf16x8*)(wp + (1 * 16 + la) * 520);
      bf16x8 b2 = *(const bf16x8*)(wp + (2 * 16 + la) * 520);
      acc0 = __builtin_amdgcn_mfma_f32_16x16x32_bf16(af[q], b0, acc0, 0, 0, 0);
      acc1 = __builtin_amdgcn_mfma_f32_16x16x32_bf16(af[q], b1, acc1, 0, 0, 0);
      acc2 = __builtin_amdgcn_mfma_f32_16x16x32_bf16(af[q], b2, acc2, 0, 0, 0);
    }
    float h1v[4];
#pragma unroll
    for (int r = 0; r < 4; ++r) {
      const float ghr = acc0[r] + blr;
      const float ghz = acc1[r] + blz;
      const float ghn = acc2[r] + bln;
      const float rr = 1.f / (1.f + expf(-(gv[r * 3 + 0] + ghr)));
      const float zz = 1.f / (1.f + expf(-(gv[r * 3 + 1] + ghz)));
      const float nn = tanhf(gv[r * 3 + 2] + rr * ghn);
      h1v[r] = (1.f - zz) * nn + zz * hprev[r];
      hprev[r] = h1v[r];
    }
    unsigned int* hn = hbuf + (size_t)((t + 1) & 1) * 16384 + blk * 512;
#pragma unroll
    for (int r = 0; r < 4; ++r) {
      const int row = wv * 16 + lg * 4 + r;
      const unsigned int mine =
          (unsigned int)__builtin_bit_cast(unsigned short, (bf16_t)h1v[r]);
      const unsigned int other = (unsigned int)__shfl_xor((int)mine, 1);
      if ((la & 1) == 0) {
        __hip_atomic_store(hn + row * 8 + (la >> 1), mine | (other << 16),
                           __ATOMIC_RELAXED, __HIP_MEMORY_SCOPE_AGENT);
      }
    }
    asm volatile("s_waitcnt vmcnt(0)" ::: "memory");
    if (lane == 0) {
      __hip_atomic_store(&flags[(blk * 4 + wv) * 16], t + 1, __ATOMIC_RELAXED,
                         __HIP_MEMORY_SCOPE_AGENT);
    }
#pragma unroll
    for (int r = 0; r < 4; ++r) {
      const int row = wv * 16 + lg * 4 + r;
      Xall[((size_t)t * BATCH + row) * HID + jcol] = (bf16_t)(h1v[r] * ctv[r]);
    }
  }
}

// ---------------------------------------------------------------------------
__global__ __launch_bounds__(256) void attn_k(const bf16_t* __restrict__ QKV,
                                              bf16_t* __restrict__ attO)
{
  __shared__ float sq[4][512], sk[4][512], sv[4][512], sw[4][64];
  const int tid = threadIdx.x;
  const int wv = tid >> 6, lane = tid & 63;
  const int row = blockIdx.x * 4 + wv;
  const bf16_t* base = QKV + (size_t)row * G3;
  bf16x8 vq = *(const bf16x8*)(base + lane * 8);
  bf16x8 vk = *(const bf16x8*)(base + 512 + lane * 8);
  bf16x8 vv = *(const bf16x8*)(base + 1024 + lane * 8);
#pragma unroll
  for (int e = 0; e < 8; ++e) {
    sq[wv][lane * 8 + e] = (float)vq[e];
    sk[wv][lane * 8 + e] = (float)vk[e];
    sv[wv][lane * 8 + e] = (float)vv[e];
  }
  __syncthreads();
  const int h = lane >> 3, g = lane & 7;
  float s = 0.f;
#pragma unroll 16
  for (int d = 0; d < 64; ++d) s += sq[wv][h * 64 + d] * sk[wv][g * 64 + d];
  s *= (1.f / 64.f);
  float m = s;
  m = fmaxf(m, __shfl_xor(m, 1));
  m = fmaxf(m, __shfl_xor(m, 2));
  m = fmaxf(m, __shfl_xor(m, 4));
  const float e = expf(s - m);
  float sum = e;
  sum += __shfl_xor(sum, 1);
  sum += __shfl_xor(sum, 2);
  sum += __shfl_xor(sum, 4);
  sw[wv][lane] = e / sum;
  __syncthreads();
#pragma unroll
  for (int rep = 0; rep < 8; ++rep) {
    const int idx = rep * 64 + lane;
    const int hh = idx >> 6, d = idx & 63;
    float o = 0.f;
#pragma unroll
    for (int gg = 0; gg < 8; ++gg) o += sw[wv][hh * 8 + gg] * sv[wv][gg * 64 + d];
    attO[(size_t)row * HID + idx] = (bf16_t)o;
  }
}

// --------------------------- small prep kernels ----------------------------
__global__ __launch_bounds__(256) void cast5_k(
    const float* __restrict__ s0, const float* __restrict__ s1,
    const float* __restrict__ s2, const float* __restrict__ s3,
    const float* __restrict__ s4, bf16_t* __restrict__ Wqkv,
    bf16_t* __restrict__ WfcB, bf16_t* __restrict__ Wh2oB)
{
  const int seg = blockIdx.x >> 8;
  const int i = (blockIdx.x & 255) * 256 + threadIdx.x;
  const float* src = seg == 0 ? s0 : seg == 1 ? s1 : seg == 2 ? s2
                   : seg == 3 ? s3 : s4;
  bf16_t* dst = seg <= 2 ? Wqkv + (size_t)seg * HID * DIN
              : seg == 3 ? WfcB : Wh2oB;
  float4 v = ((const float4*)src)[i];
  bf16x4 o = {(bf16_t)v.x, (bf16_t)v.y, (bf16_t)v.z, (bf16_t)v.w};
  *(bf16x4*)(dst + (size_t)i * 4) = o;
}

__global__ __launch_bounds__(256) void perm_cast_k(const float* __restrict__ src,
                                                   bf16_t* __restrict__ dst)
{
  const int i = blockIdx.x * 256 + threadIdx.x;
  const int pg = i >> 7, kq = (i & 127) << 2;
  const int g = pg / 48, rem = pg - g * 48, sec = rem >> 4, jj = rem & 15;
  const int srow = sec * 512 + g * 16 + jj;
  float4 v = *(const float4*)(src + (size_t)srow * DIN + kq);
  bf16x4 o = {(bf16_t)v.x, (bf16_t)v.y, (bf16_t)v.z, (bf16_t)v.w};
  *(bf16x4*)(dst + (size_t)pg * DIN + kq) = o;
}

__global__ void perm_bias_k(const float* __restrict__ bih, const float* __restrict__ bhh,
                            float* __restrict__ bihp, float* __restrict__ bhhp)
{
  const int pg = blockIdx.x * 256 + threadIdx.x;
  if (pg >= G3) return;
  const int g = pg / 48, rem = pg - g * 48, sec = rem >> 4, jj = rem & 15;
  const int srow = sec * 512 + g * 16 + jj;
  bihp[pg] = bih[srow];
  bhhp[pg] = bhh[srow];
}

__global__ void bcat_k(const float* __restrict__ a, const float* __restrict__ b,
                       const float* __restrict__ c, float* __restrict__ d)
{
  const int i = blockIdx.x * 256 + threadIdx.x;
  if (i >= G3) return;
  d[i] = i < 512 ? a[i] : (i < 1024 ? b[i - 512] : c[i - 1024]);
}

__global__ __launch_bounds__(256) void yemb_k(const int* __restrict__ y,
                                              const float* __restrict__ embW,
                                              bf16_t* __restrict__ out)
{
  const int idx = blockIdx.x * 256 + threadIdx.x;
  const int rb = idx >> 6, c = (idx & 63) << 3;
  const int tok = y[rb];
  const float4* s = (const float4*)(embW + (size_t)tok * DIN + c);
  float4 v0 = s[0], v1 = s[1];
  bf16x8 o = {(bf16_t)v0.x, (bf16_t)v0.y, (bf16_t)v0.z, (bf16_t)v0.w,
              (bf16_t)v1.x, (bf16_t)v1.y, (bf16_t)v1.z, (bf16_t)v1.w};
  *(bf16x8*)(out + (size_t)rb * DIN + c) = o;
}

__global__ __launch_bounds__(256) void ct_k(const float* __restrict__ ctx,
                                            const float* __restrict__ Watt,
                                            const float* __restrict__ batt,
                                            float* __restrict__ ct)
{
  const int idx = blockIdx.x * 256 + threadIdx.x;
  const int b = idx >> 9, j = idx & 511;
  const float4* c4 = (const float4*)(ctx + (size_t)b * FFEAT);
  const float4* w4 = (const float4*)(Watt + (size_t)j * FFEAT);
  float s = batt[j];
  for (int q = 0; q < FFEAT / 4; ++q) {
    float4 cc = c4[q], ww = w4[q];
    s += cc.x * ww.x + cc.y * ww.y + cc.z * ww.z + cc.w * ww.w;
  }
  ct[idx] = tanhf(s);
}

__global__ __launch_bounds__(256) void reduce_rows(const float* __restrict__ partial,
                                                   float* __restrict__ rowsum, int NB)
{
  const int wv = threadIdx.x >> 6, lane = threadIdx.x & 63;
  const int row = blockIdx.x * 4 + wv;
  float s = 0.f;
  for (int c = lane; c < NB; c += 64) s += partial[(size_t)row * NB + c];
  for (int m = 1; m < 64; m <<= 1) s += __shfl_xor(s, m);
  if (lane == 0) rowsum[row] = s;
}

__global__ __launch_bounds__(256) void normalize_k(const bf16_t* __restrict__ e,
                                                   const float* __restrict__ rowsum,
                                                   float* __restrict__ out)
{
  const int row = blockIdx.y;
  const int c8 = blockIdx.x * 256 + threadIdx.x;
  if (c8 >= VOCAB / 8) return;
  const float inv = 1.0f / rowsum[row];
  const size_t base = (size_t)row * VOCAB + (size_t)c8 * 8;
  bf16x8 v = *(const bf16x8*)(e + base);
  float4 o0 = {(float)v[0] * inv, (float)v[1] * inv, (float)v[2] * inv, (float)v[3] * inv};
  float4 o1 = {(float)v[4] * inv, (float)v[5] * inv, (float)v[6] * inv, (float)v[7] * inv};
  *(float4*)(out + base) = o0;
  *(float4*)(out + base + 4) = o1;
}

// ---------------------------------------------------------------------------
extern "C" void kernel_launch(void* const* d_in, const int* in_sizes, int n_in,
                              void* d_out, int out_size, void* d_ws, size_t ws_size,
                              hipStream_t stream)
{
  const int*   y     = (const int*)  d_in[0];
  const float* ctx   = (const float*)d_in[1];
  const float* embW  = (const float*)d_in[2];
  const float* W_ih  = (const float*)d_in[3];
  const float* b_ih  = (const float*)d_in[4];
  const float* W_hh  = (const float*)d_in[5];
  const float* b_hh  = (const float*)d_in[6];
  const float* W_att = (const float*)d_in[7];
  const float* b_att = (const float*)d_in[8];
  const float* Wq    = (const float*)d_in[9];
  const float* bq    = (const float*)d_in[10];
  const float* Wk    = (const float*)d_in[11];
  const float* bk    = (const float*)d_in[12];
  const float* Wv    = (const float*)d_in[13];
  const float* bv    = (const float*)d_in[14];
  const float* Wfc   = (const float*)d_in[15];
  const float* bfc   = (const float*)d_in[16];
  const float* Wh2o  = (const float*)d_in[17];
  const float* bh2o  = (const float*)d_in[18];
  const float* W_out = (const float*)d_in[19];
  const float* b_out = (const float*)d_in[20];

  char* p = (char*)d_ws;
  auto alloc = [&](size_t bytes) {
    char* r = p;
    p += (bytes + 255) & ~(size_t)255;
    return r;
  };
  bf16_t* WoutB   = (bf16_t*)alloc((size_t)VOCAB * DIN * 2);
  bf16_t* WgIh    = (bf16_t*)alloc((size_t)G3 * DIN * 2);
  bf16_t* WgHh    = (bf16_t*)alloc((size_t)G3 * DIN * 2);
  bf16_t* Wqkv    = (bf16_t*)alloc((size_t)G3 * DIN * 2);
  bf16_t* WfcB    = (bf16_t*)alloc((size_t)HID * HID * 2);
  bf16_t* Wh2oB   = (bf16_t*)alloc((size_t)HID * HID * 2);
  float*  bIhP    = (float*)alloc(G3 * 4);
  float*  bHhP    = (float*)alloc(G3 * 4);
  float*  bQkv    = (float*)alloc(G3 * 4);
  bf16_t* Yemb    = (bf16_t*)alloc((size_t)ROWS * DIN * 2);
  float*  giP     = (float*)alloc((size_t)ROWS * G3 * 4);
  float*  ctB     = (float*)alloc((size_t)BATCH * HID * 4);
  unsigned int* hbuf = (unsigned int*)alloc((size_t)2 * 16384 * 4);
  bf16_t* Xall    = (bf16_t*)alloc((size_t)ROWS * DIN * 2);
  bf16_t* QKV     = (bf16_t*)alloc((size_t)ROWS * G3 * 2);
  bf16_t* attO    = (bf16_t*)alloc((size_t)ROWS * HID * 2);
  bf16_t* h2B     = (bf16_t*)alloc((size_t)ROWS * HID * 2);
  bf16_t* logit   = (bf16_t*)alloc((size_t)ROWS * DIN * 2);
  float*  partial = (float*)alloc((size_t)ROWS * 125 * 4);
  float*  rowsum  = (float*)alloc((size_t)ROWS * 4);
  int*    flags   = (int*)alloc(16384);        // h-flags [0,8K) + gi-flags [8K,9K)
  bf16_t* eCache  = (bf16_t*)alloc((size_t)ROWS * VOCAB * 2);   // 131 MB

  hipMemsetAsync(hbuf, 0, (size_t)2 * 16384 * 4, stream);
  hipMemsetAsync(flags, 0, 16384, stream);

  // weight prep (gi-GEMM + W_out cast fused into phaseA launch below)
  cast5_k<<<1280, 256, 0, stream>>>(Wq, Wk, Wv, Wfc, Wh2o, Wqkv, WfcB, Wh2oB);
  perm_cast_k<<<768, 256, 0, stream>>>(W_ih, WgIh);
  perm_cast_k<<<768, 256, 0, stream>>>(W_hh, WgHh);
  perm_bias_k<<<6, 256, 0, stream>>>(b_ih, b_hh, bIhP, bHhP);
  bcat_k<<<6, 256, 0, stream>>>(bq, bk, bv, bQkv);
  yemb_k<<<512, 256, 0, stream>>>(y, embW, Yemb);
  ct_k<<<128, 256, 0, stream>>>(ctx, W_att, b_att, ctB);

  // GRU recurrence (0-31) + gi producers (32-223, then W_out cast)
  phaseA_k<<<NBLK_A + NBLK_GI, 256, 0, stream>>>(
      WgHh, bHhP, giP, ctB, hbuf, Xall, flags, W_out, WoutB, Yemb, WgIh, bIhP);

  // QKV = X @ [Wq;Wk;Wv]^T + b
  gemm_lds<EPI_BF16, DIN><<<dim3(12, 16), 256, 0, stream>>>(
      Xall, Wqkv, bQkv, QKV, ROWS, G3);

  attn_k<<<512, 256, 0, stream>>>(QKV, attO);

  gemm_lds<EPI_BF16, HID><<<dim3(4, 16), 256, 0, stream>>>(
      attO, WfcB, bfc, h2B, ROWS, HID);

  gemm_lds<EPI_TANH, HID><<<dim3(4, 16), 256, 0, stream>>>(
      h2B, Wh2oB, bh2o, logit, ROWS, DIN);

  // vocab: single GEMM -> bf16 exp cache + partial sums (NB = 125)
  gemm_v<DIN><<<1000, 512, 0, stream>>>(
      logit, WoutB, b_out, eCache, partial, ROWS, VOCAB, 125);
  reduce_rows<<<512, 256, 0, stream>>>(partial, rowsum, 125);
  normalize_k<<<dim3(16, ROWS), 256, 0, stream>>>(eCache, rowsum, (float*)d_out);
}